// Round 1
// baseline (555.774 us; speedup 1.0000x reference)
//
#include <hip/hip_runtime.h>
#include <hip/hip_bf16.h>

#define SEQ 2048
#define DM 2048
#define NH 16
#define NKV 4
#define HD 128

typedef float f32x4 __attribute__((ext_vector_type(4)));
typedef short s16x8 __attribute__((ext_vector_type(8)));

__device__ inline __hip_bfloat16 f2b(float f) { return __float2bfloat16(f); }

// ---------------- cast fp32 -> bf16 ----------------
__global__ void cast_kernel(const float* __restrict__ in, __hip_bfloat16* __restrict__ out, int n) {
    int i = (blockIdx.x * 256 + threadIdx.x) * 4;
    if (i < n) {
        float4 v = *(const float4*)(in + i);
        __hip_bfloat16 o4[4] = {f2b(v.x), f2b(v.y), f2b(v.z), f2b(v.w)};
        *(ushort4*)(out + i) = *(ushort4*)o4;
    }
}

// ---------------- transpose + cast: in[K][N] fp32 -> out[N][K] bf16 ----------------
__global__ void transpose_cast(const float* __restrict__ in, __hip_bfloat16* __restrict__ out,
                               int K, int N) {
    __shared__ float tile[32][33];
    int n0 = blockIdx.x * 32, k0 = blockIdx.y * 32;
    int tx = threadIdx.x, ty = threadIdx.y; // block (32,8)
    for (int r = ty; r < 32; r += 8)
        tile[r][tx] = in[(size_t)(k0 + r) * N + n0 + tx];
    __syncthreads();
    for (int r = ty; r < 32; r += 8)
        out[(size_t)(n0 + r) * K + k0 + tx] = f2b(tile[tx][r]);
}

// ---------------- GEMM: C[M][N] = A[M][Kd] * Bt[N][Kd]^T, bf16 in, fp32 acc ----------------
template <int OUT_F32>
__global__ __launch_bounds__(256, 2) void gemm_bt(
    const __hip_bfloat16* __restrict__ A,
    const __hip_bfloat16* __restrict__ Bt,
    void* __restrict__ Cp, int M, int N, int Kd) {
    __shared__ __hip_bfloat16 As[128][72]; // stride 144B = 9*16B: aligned, 2-way banks
    __shared__ __hip_bfloat16 Bs[128][72];
    const int m0 = blockIdx.y * 128, n0 = blockIdx.x * 128;
    const int t = threadIdx.x;
    const int wv = t >> 6, lane = t & 63;
    const int wm = (wv >> 1) * 64, wn = (wv & 1) * 64;
    const int lrow = lane & 15, quad = lane >> 4;
    f32x4 acc[4][4];
    f32x4 z4 = {0.f, 0.f, 0.f, 0.f};
    for (int i = 0; i < 4; ++i)
        for (int j = 0; j < 4; ++j) acc[i][j] = z4;

    for (int k0 = 0; k0 < Kd; k0 += 64) {
        __syncthreads();
        for (int i = 0; i < 4; ++i) {
            int flat = (i * 256 + t) * 8;
            int row = flat >> 6, col = flat & 63;
            *(s16x8*)&As[row][col] = *(const s16x8*)(A + (size_t)(m0 + row) * Kd + k0 + col);
            *(s16x8*)&Bs[row][col] = *(const s16x8*)(Bt + (size_t)(n0 + row) * Kd + k0 + col);
        }
        __syncthreads();
        s16x8 af[2][4], bf[2][4];
        for (int kk = 0; kk < 2; ++kk)
            for (int i = 0; i < 4; ++i) {
                af[kk][i] = *(const s16x8*)&As[wm + i * 16 + lrow][kk * 32 + quad * 8];
                bf[kk][i] = *(const s16x8*)&Bs[wn + i * 16 + lrow][kk * 32 + quad * 8];
            }
        for (int kk = 0; kk < 2; ++kk)
            for (int i = 0; i < 4; ++i)
                for (int j = 0; j < 4; ++j)
                    acc[i][j] = __builtin_amdgcn_mfma_f32_16x16x32_bf16(af[kk][i], bf[kk][j],
                                                                        acc[i][j], 0, 0, 0);
    }
    // C layout: col = lane&15, row = quad*4 + reg  [guide §3, m89-verified]
    for (int i = 0; i < 4; ++i)
        for (int j = 0; j < 4; ++j)
            for (int r = 0; r < 4; ++r) {
                int m = m0 + wm + i * 16 + quad * 4 + r;
                int n = n0 + wn + j * 16 + lrow;
                if (OUT_F32)
                    ((float*)Cp)[(size_t)m * N + n] = acc[i][j][r];
                else
                    ((__hip_bfloat16*)Cp)[(size_t)m * N + n] = f2b(acc[i][j][r]);
            }
}

// ---------------- RoPE + reshape ----------------
// qkv[4096][3072] -> q[b][h][s][d], k[b][kv][s][d], vt[b][kv][d][s]
__global__ void rope_reshape(const __hip_bfloat16* __restrict__ qkv,
                             const float* __restrict__ fcos, const float* __restrict__ fsin,
                             __hip_bfloat16* __restrict__ q, __hip_bfloat16* __restrict__ k,
                             __hip_bfloat16* __restrict__ vt) {
    int tok = blockIdx.x; // b*SEQ + s
    int b = tok >> 11, s = tok & 2047;
    const __hip_bfloat16* row = qkv + (size_t)tok * 3072;
    for (int pp = threadIdx.x; pp < 1536; pp += 256) {
        int col = pp * 2;
        float x0 = __bfloat162float(row[col]);
        float x1 = __bfloat162float(row[col + 1]);
        if (col < 2560) { // q or k: rope
            int d = col & 127;
            int p = d >> 1;
            float c = fcos[s * 64 + p], sn = fsin[s * 64 + p];
            float o0 = x0 * c - x1 * sn;
            float o1 = x0 * sn + x1 * c;
            if (col < 2048) {
                int h = col >> 7;
                size_t o = ((size_t)((b * NH + h) * SEQ + s)) * HD + d;
                q[o] = f2b(o0);
                q[o + 1] = f2b(o1);
            } else {
                int h = (col - 2048) >> 7;
                size_t o = ((size_t)((b * NKV + h) * SEQ + s)) * HD + d;
                k[o] = f2b(o0);
                k[o + 1] = f2b(o1);
            }
        } else {
            int cv = col - 2560;
            int h = cv >> 7, d = cv & 127;
            size_t o = ((size_t)((b * NKV + h) * HD + d)) * SEQ + s;
            vt[o] = f2b(x0);
            vt[o + SEQ] = f2b(x1);
        }
    }
}

// ---------------- causal flash attention (GQA) ----------------
// q[b][h][s][d], k[b][kv][s][d], vt[b][kv][d][s] -> o[b*SEQ][NH*HD]
__global__ __launch_bounds__(256, 2) void attn_kernel(
    const __hip_bfloat16* __restrict__ q, const __hip_bfloat16* __restrict__ k,
    const __hip_bfloat16* __restrict__ vt, __hip_bfloat16* __restrict__ o) {
    __shared__ __hip_bfloat16 Ks[64][136];  // keys x d, stride 272B = 17*16B
    __shared__ __hip_bfloat16 Vs[128][72];  // d x keys
    __shared__ __hip_bfloat16 Ps[4][16][72];

    const int bx = blockIdx.x;       // q tile (64 rows)
    const int bh = blockIdx.y;       // b*NH + h
    const int b = bh >> 4, h = bh & 15;
    const int kvh = h >> 2; // REP = 4
    const int t = threadIdx.x;
    const int w = t >> 6, lane = t & 63;
    const int lrow = lane & 15, quad = lane >> 4;
    const int q0 = bx * 64;
    const float scale = 0.08838834764831845f; // 1/sqrt(128)

    // Q fragments (A-layout: m=lane&15, k=quad*8+j) straight from global
    const __hip_bfloat16* qp = q + ((size_t)((b * NH + h) * SEQ + q0 + w * 16 + lrow)) * HD;
    s16x8 qf[4];
    for (int ks = 0; ks < 4; ++ks) qf[ks] = *(const s16x8*)(qp + ks * 32 + quad * 8);

    float m_i[4], l_i[4], alpha[4];
    f32x4 accO[8];
    f32x4 z4 = {0.f, 0.f, 0.f, 0.f};
    for (int r = 0; r < 4; ++r) { m_i[r] = -1e30f; l_i[r] = 0.f; }
    for (int d = 0; d < 8; ++d) accO[d] = z4;

    const __hip_bfloat16* kbase = k + ((size_t)(b * NKV + kvh) * SEQ) * HD;
    const __hip_bfloat16* vbase = vt + ((size_t)(b * NKV + kvh) * HD) * SEQ;

    const int nkt = bx + 1; // causal: only tiles up to diagonal
    for (int kt = 0; kt < nkt; ++kt) {
        __syncthreads();
        for (int i = 0; i < 4; ++i) { // K tile: 64x128
            int flat = (i * 256 + t) * 8;
            int row = flat >> 7, col = flat & 127;
            *(s16x8*)&Ks[row][col] = *(const s16x8*)(kbase + (size_t)(kt * 64 + row) * HD + col);
        }
        for (int i = 0; i < 4; ++i) { // Vt tile: 128x64
            int flat = (i * 256 + t) * 8;
            int row = flat >> 6, col = flat & 63;
            *(s16x8*)&Vs[row][col] = *(const s16x8*)(vbase + (size_t)row * SEQ + kt * 64 + col);
        }
        __syncthreads();

        // S = Q K^T  (B operand: n=key=lane&15, k=d=quad*8+j -> Ks[key][d] contiguous)
        f32x4 S[4];
        for (int nt = 0; nt < 4; ++nt) {
            f32x4 sacc = z4;
            for (int ks = 0; ks < 4; ++ks) {
                s16x8 kf = *(const s16x8*)&Ks[nt * 16 + lrow][ks * 32 + quad * 8];
                sacc = __builtin_amdgcn_mfma_f32_16x16x32_bf16(qf[ks], kf, sacc, 0, 0, 0);
            }
            S[nt] = sacc;
        }
        bool last = (kt == bx);
        for (int nt = 0; nt < 4; ++nt) {
            int key = kt * 64 + nt * 16 + lrow;
            for (int r = 0; r < 4; ++r) {
                float v = S[nt][r] * scale;
                int qr = q0 + w * 16 + quad * 4 + r;
                if (last && key > qr) v = -1e30f;
                S[nt][r] = v;
            }
        }
        // online softmax; stats per row live in (quad, reg), replicated across 16 lanes
        for (int r = 0; r < 4; ++r) {
            float mt = fmaxf(fmaxf(S[0][r], S[1][r]), fmaxf(S[2][r], S[3][r]));
            for (int off = 1; off < 16; off <<= 1) mt = fmaxf(mt, __shfl_xor(mt, off, 64));
            float mn = fmaxf(m_i[r], mt);
            alpha[r] = __expf(m_i[r] - mn);
            m_i[r] = mn;
            float rs = 0.f;
            for (int nt = 0; nt < 4; ++nt) {
                float p = __expf(S[nt][r] - mn);
                S[nt][r] = p;
                rs += p;
            }
            for (int off = 1; off < 16; off <<= 1) rs += __shfl_xor(rs, off, 64);
            l_i[r] = l_i[r] * alpha[r] + rs;
        }
        // P: C-layout -> LDS -> A-layout (guide m120 pattern); per-wave slice, no barrier
        for (int nt = 0; nt < 4; ++nt)
            for (int r = 0; r < 4; ++r)
                Ps[w][quad * 4 + r][nt * 16 + lrow] = f2b(S[nt][r]);
        for (int d = 0; d < 8; ++d)
            for (int r = 0; r < 4; ++r) accO[d][r] *= alpha[r];
        s16x8 pf0 = *(const s16x8*)&Ps[w][lrow][quad * 8];
        s16x8 pf1 = *(const s16x8*)&Ps[w][lrow][32 + quad * 8];
        for (int dt = 0; dt < 8; ++dt) {
            s16x8 vf0 = *(const s16x8*)&Vs[dt * 16 + lrow][quad * 8];
            s16x8 vf1 = *(const s16x8*)&Vs[dt * 16 + lrow][32 + quad * 8];
            accO[dt] = __builtin_amdgcn_mfma_f32_16x16x32_bf16(pf0, vf0, accO[dt], 0, 0, 0);
            accO[dt] = __builtin_amdgcn_mfma_f32_16x16x32_bf16(pf1, vf1, accO[dt], 0, 0, 0);
        }
    }
    // epilogue: o[b*SEQ + qr][h*HD + d]
    for (int dt = 0; dt < 8; ++dt)
        for (int r = 0; r < 4; ++r) {
            int qr = q0 + w * 16 + quad * 4 + r;
            size_t oi = ((size_t)(b * SEQ + qr)) * DM + h * HD + dt * 16 + lrow;
            o[oi] = f2b(accO[dt][r] / l_i[r]);
        }
}

extern "C" void kernel_launch(void* const* d_in, const int* in_sizes, int n_in,
                              void* d_out, int out_size, void* d_ws, size_t ws_size,
                              hipStream_t stream) {
    (void)in_sizes; (void)n_in; (void)out_size; (void)ws_size;
    const float* x  = (const float*)d_in[0];
    const float* fc = (const float*)d_in[1];
    const float* fs = (const float*)d_in[2];
    // d_in[3] = mask: exactly causal, applied analytically
    const float* wq = (const float*)d_in[4];
    const float* wk = (const float*)d_in[5];
    const float* wv = (const float*)d_in[6];
    const float* wo = (const float*)d_in[7];

    // workspace layout (bf16 elems), with stage-lifetime aliasing; total ~60 MB
    __hip_bfloat16* xb    = (__hip_bfloat16*)d_ws;            // [4096][2048]
    __hip_bfloat16* wqkvt = xb + (size_t)8388608;             // [3072][2048]
    __hip_bfloat16* wot   = wqkvt + (size_t)6291456;          // [2048][2048]
    __hip_bfloat16* qkv   = wot + (size_t)4194304;            // [4096][3072]
    __hip_bfloat16* qb    = xb;                               // [2][16][2048][128] (aliases xb)
    __hip_bfloat16* kb    = wqkvt;                            // [2][4][2048][128]  (aliases wqkvt)
    __hip_bfloat16* vtb   = wqkvt + (size_t)2097152;          // [2][4][128][2048]
    __hip_bfloat16* attno = qkv;                              // [4096][2048] (aliases qkv)

    // S1: casts + weight transposes
    cast_kernel<<<8192, 256, 0, stream>>>(x, xb, 8388608);
    transpose_cast<<<dim3(64, 64), dim3(32, 8), 0, stream>>>(wq, wqkvt, 2048, 2048);
    transpose_cast<<<dim3(16, 64), dim3(32, 8), 0, stream>>>(wk, wqkvt + (size_t)2048 * 2048, 2048, 512);
    transpose_cast<<<dim3(16, 64), dim3(32, 8), 0, stream>>>(wv, wqkvt + (size_t)2560 * 2048, 2048, 512);
    transpose_cast<<<dim3(64, 64), dim3(32, 8), 0, stream>>>(wo, wot, 2048, 2048);
    // S2: qkv = x @ [wq|wk|wv]
    gemm_bt<0><<<dim3(24, 32), 256, 0, stream>>>(xb, wqkvt, qkv, 4096, 3072, 2048);
    // S3: rope + reshape
    rope_reshape<<<4096, 256, 0, stream>>>(qkv, fc, fs, qb, kb, vtb);
    // S4: causal GQA flash attention
    attn_kernel<<<dim3(32, 32), 256, 0, stream>>>(qb, kb, vtb, attno);
    // S5: out = attno @ wo (fp32 out)
    gemm_bt<1><<<dim3(16, 32), 256, 0, stream>>>(attno, wot, d_out, 4096, 2048, 2048);
}

// Round 2
// 455.061 us; speedup vs baseline: 1.2213x; 1.2213x over previous
//
#include <hip/hip_runtime.h>
#include <hip/hip_bf16.h>

#define SEQ 2048
#define DM 2048
#define NH 16
#define NKV 4
#define HD 128

typedef float f32x4 __attribute__((ext_vector_type(4)));
typedef short s16x8 __attribute__((ext_vector_type(8)));

__device__ inline __hip_bfloat16 f2b(float f) { return __float2bfloat16(f); }

// ---------------- cast fp32 -> bf16 ----------------
__global__ void cast_kernel(const float* __restrict__ in, __hip_bfloat16* __restrict__ out, int n) {
    int i = (blockIdx.x * 256 + threadIdx.x) * 4;
    if (i < n) {
        float4 v = *(const float4*)(in + i);
        __hip_bfloat16 o4[4] = {f2b(v.x), f2b(v.y), f2b(v.z), f2b(v.w)};
        *(ushort4*)(out + i) = *(ushort4*)o4;
    }
}

// ---------------- transpose + cast: in[K][N] fp32 -> out[N][K] bf16 ----------------
__global__ void transpose_cast(const float* __restrict__ in, __hip_bfloat16* __restrict__ out,
                               int K, int N) {
    __shared__ float tile[32][33];
    int n0 = blockIdx.x * 32, k0 = blockIdx.y * 32;
    int tx = threadIdx.x, ty = threadIdx.y; // block (32,8)
    for (int r = ty; r < 32; r += 8)
        tile[r][tx] = in[(size_t)(k0 + r) * N + n0 + tx];
    __syncthreads();
    for (int r = ty; r < 32; r += 8)
        out[(size_t)(n0 + r) * K + k0 + tx] = f2b(tile[tx][r]);
}

// ---------------- GEMM: C[M][N] = A[M][Kd] * Bt[N][Kd]^T, bf16 in, fp32 acc ----------------
// Register-prefetch pipeline: global loads for tile t+1 issue before MFMA on tile t.
template <int OUT_F32>
__global__ __launch_bounds__(256, 2) void gemm_bt(
    const __hip_bfloat16* __restrict__ A,
    const __hip_bfloat16* __restrict__ Bt,
    void* __restrict__ Cp, int M, int N, int Kd) {
    __shared__ __hip_bfloat16 As[128][72]; // stride 144B: 16B-aligned rows, 2-way banks (free)
    __shared__ __hip_bfloat16 Bs[128][72];
    const int m0 = blockIdx.y * 128, n0 = blockIdx.x * 128;
    const int t = threadIdx.x;
    const int wv = t >> 6, lane = t & 63;
    const int wm = (wv >> 1) * 64, wn = (wv & 1) * 64;
    const int lrow = lane & 15, quad = lane >> 4;
    f32x4 acc[4][4];
    f32x4 z4 = {0.f, 0.f, 0.f, 0.f};
    for (int i = 0; i < 4; ++i)
        for (int j = 0; j < 4; ++j) acc[i][j] = z4;

    s16x8 ar[4], br[4];
    auto load_tile = [&](int k0) {
        for (int i = 0; i < 4; ++i) {
            int flat = (i * 256 + t) * 8;
            int row = flat >> 6, col = flat & 63;
            ar[i] = *(const s16x8*)(A + (size_t)(m0 + row) * Kd + k0 + col);
            br[i] = *(const s16x8*)(Bt + (size_t)(n0 + row) * Kd + k0 + col);
        }
    };
    auto store_tile = [&]() {
        for (int i = 0; i < 4; ++i) {
            int flat = (i * 256 + t) * 8;
            int row = flat >> 6, col = flat & 63;
            *(s16x8*)&As[row][col] = ar[i];
            *(s16x8*)&Bs[row][col] = br[i];
        }
    };

    load_tile(0);
    store_tile();
    __syncthreads();

    for (int k0 = 0; k0 < Kd; k0 += 64) {
        bool more = (k0 + 64) < Kd;
        if (more) load_tile(k0 + 64); // in flight across frag reads + MFMA
        s16x8 af[2][4], bf[2][4];
        for (int kk = 0; kk < 2; ++kk)
            for (int i = 0; i < 4; ++i) {
                af[kk][i] = *(const s16x8*)&As[wm + i * 16 + lrow][kk * 32 + quad * 8];
                bf[kk][i] = *(const s16x8*)&Bs[wn + i * 16 + lrow][kk * 32 + quad * 8];
            }
        for (int kk = 0; kk < 2; ++kk)
            for (int i = 0; i < 4; ++i)
                for (int j = 0; j < 4; ++j)
                    acc[i][j] = __builtin_amdgcn_mfma_f32_16x16x32_bf16(af[kk][i], bf[kk][j],
                                                                        acc[i][j], 0, 0, 0);
        __syncthreads();
        if (more) {
            store_tile();
            __syncthreads();
        }
    }
    // C layout: col = lane&15, row = quad*4 + reg  [guide §3, m89-verified]
    for (int i = 0; i < 4; ++i)
        for (int j = 0; j < 4; ++j)
            for (int r = 0; r < 4; ++r) {
                int m = m0 + wm + i * 16 + quad * 4 + r;
                int n = n0 + wn + j * 16 + lrow;
                if (OUT_F32)
                    ((float*)Cp)[(size_t)m * N + n] = acc[i][j][r];
                else
                    ((__hip_bfloat16*)Cp)[(size_t)m * N + n] = f2b(acc[i][j][r]);
            }
}

// ---------------- RoPE + reshape (q, k only) ----------------
__global__ void rope_reshape(const __hip_bfloat16* __restrict__ qkv,
                             const float* __restrict__ fcos, const float* __restrict__ fsin,
                             __hip_bfloat16* __restrict__ q, __hip_bfloat16* __restrict__ k) {
    int tok = blockIdx.x; // b*SEQ + s
    int b = tok >> 11, s = tok & 2047;
    const __hip_bfloat16* row = qkv + (size_t)tok * 3072;
    for (int pp = threadIdx.x; pp < 1280; pp += 256) {
        int col = pp * 2;
        float x0 = __bfloat162float(row[col]);
        float x1 = __bfloat162float(row[col + 1]);
        int d = col & 127;
        int p = d >> 1;
        float c = fcos[s * 64 + p], sn = fsin[s * 64 + p];
        float o0 = x0 * c - x1 * sn;
        float o1 = x0 * sn + x1 * c;
        if (col < 2048) {
            int h = col >> 7;
            size_t o = ((size_t)((b * NH + h) * SEQ + s)) * HD + d;
            q[o] = f2b(o0);
            q[o + 1] = f2b(o1);
        } else {
            int h = (col - 2048) >> 7;
            size_t o = ((size_t)((b * NKV + h) * SEQ + s)) * HD + d;
            k[o] = f2b(o0);
            k[o + 1] = f2b(o1);
        }
    }
}

// ---------------- V transpose via LDS: qkv v-cols -> vt[b][kv][d][s] ----------------
__global__ void vtrans(const __hip_bfloat16* __restrict__ qkv, __hip_bfloat16* __restrict__ vt) {
    __shared__ __hip_bfloat16 tile[128][136];
    int s0 = blockIdx.x * 128;          // 16 s-tiles
    int bh = blockIdx.y;                // b*NKV + kvh
    int b = bh >> 2, kvh = bh & 3;
    int t = threadIdx.x;
    for (int i = 0; i < 8; ++i) {
        int flat = (i * 256 + t) * 8;   // 128x128 elems
        int row = flat >> 7, col = flat & 127;
        *(s16x8*)&tile[row][col] =
            *(const s16x8*)(qkv + (size_t)(b * SEQ + s0 + row) * 3072 + 2560 + kvh * 128 + col);
    }
    __syncthreads();
    for (int i = 0; i < 8; ++i) {
        int dd = i * 16 + (t >> 4);
        int ss = (t & 15) * 8;
        __hip_bfloat16 tmp[8];
        for (int j = 0; j < 8; ++j) tmp[j] = tile[ss + j][dd];
        *(s16x8*)(vt + ((size_t)((b * NKV + kvh) * HD + dd)) * SEQ + s0 + ss) = *(s16x8*)tmp;
    }
}

// ---------------- causal flash attention (GQA), register-prefetch pipelined ----------------
__global__ __launch_bounds__(256, 3) void attn_kernel(
    const __hip_bfloat16* __restrict__ q, const __hip_bfloat16* __restrict__ k,
    const __hip_bfloat16* __restrict__ vt, __hip_bfloat16* __restrict__ o) {
    __shared__ __hip_bfloat16 Ks[64][136];  // keys x d
    __shared__ __hip_bfloat16 Vs[128][72];  // d x keys
    __shared__ __hip_bfloat16 Ps[4][16][72];

    const int bx = (gridDim.x - 1) - blockIdx.x; // heavy (long-diagonal) blocks dispatch first
    const int bh = blockIdx.y;       // b*NH + h
    const int b = bh >> 4, h = bh & 15;
    const int kvh = h >> 2; // REP = 4
    const int t = threadIdx.x;
    const int w = t >> 6, lane = t & 63;
    const int lrow = lane & 15, quad = lane >> 4;
    const int q0 = bx * 64;
    const float scale = 0.08838834764831845f; // 1/sqrt(128)

    // Q fragments (A-layout: m=lane&15, k=quad*8+j) straight from global
    const __hip_bfloat16* qp = q + ((size_t)((b * NH + h) * SEQ + q0 + w * 16 + lrow)) * HD;
    s16x8 qf[4];
    for (int ks = 0; ks < 4; ++ks) qf[ks] = *(const s16x8*)(qp + ks * 32 + quad * 8);

    float m_i[4], l_i[4], alpha[4];
    f32x4 accO[8];
    f32x4 z4 = {0.f, 0.f, 0.f, 0.f};
    for (int r = 0; r < 4; ++r) { m_i[r] = -1e30f; l_i[r] = 0.f; }
    for (int d = 0; d < 8; ++d) accO[d] = z4;

    const __hip_bfloat16* kbase = k + ((size_t)(b * NKV + kvh) * SEQ) * HD;
    const __hip_bfloat16* vbase = vt + ((size_t)(b * NKV + kvh) * HD) * SEQ;

    s16x8 kr[4], vr[4];
    auto load_tile = [&](int kt) {
        for (int i = 0; i < 4; ++i) {
            int flat = (i * 256 + t) * 8;
            kr[i] = *(const s16x8*)(kbase + (size_t)(kt * 64 + (flat >> 7)) * HD + (flat & 127));
            vr[i] = *(const s16x8*)(vbase + (size_t)(flat >> 6) * SEQ + kt * 64 + (flat & 63));
        }
    };
    auto store_tile = [&]() {
        for (int i = 0; i < 4; ++i) {
            int flat = (i * 256 + t) * 8;
            *(s16x8*)&Ks[flat >> 7][flat & 127] = kr[i];
            *(s16x8*)&Vs[flat >> 6][flat & 63] = vr[i];
        }
    };

    const int nkt = bx + 1; // causal: only tiles up to diagonal
    load_tile(0);
    store_tile();
    __syncthreads();

    for (int kt = 0; kt < nkt; ++kt) {
        bool more = (kt + 1) < nkt;
        if (more) load_tile(kt + 1); // global loads in flight across the whole step

        // S = Q K^T  (B operand: n=key=lane&15, k=d=quad*8+j -> Ks[key][d] contiguous)
        f32x4 S[4];
        for (int nt = 0; nt < 4; ++nt) {
            f32x4 sacc = z4;
            for (int ks = 0; ks < 4; ++ks) {
                s16x8 kf = *(const s16x8*)&Ks[nt * 16 + lrow][ks * 32 + quad * 8];
                sacc = __builtin_amdgcn_mfma_f32_16x16x32_bf16(qf[ks], kf, sacc, 0, 0, 0);
            }
            S[nt] = sacc;
        }
        bool last = (kt == bx);
        for (int nt = 0; nt < 4; ++nt) {
            int key = kt * 64 + nt * 16 + lrow;
            for (int r = 0; r < 4; ++r) {
                float v = S[nt][r] * scale;
                int qr = q0 + w * 16 + quad * 4 + r;
                if (last && key > qr) v = -1e30f;
                S[nt][r] = v;
            }
        }
        // online softmax; stats per row live in (quad, reg), replicated across 16 lanes
        for (int r = 0; r < 4; ++r) {
            float mt = fmaxf(fmaxf(S[0][r], S[1][r]), fmaxf(S[2][r], S[3][r]));
            for (int off = 1; off < 16; off <<= 1) mt = fmaxf(mt, __shfl_xor(mt, off, 64));
            float mn = fmaxf(m_i[r], mt);
            alpha[r] = __expf(m_i[r] - mn);
            m_i[r] = mn;
            float rs = 0.f;
            for (int nt = 0; nt < 4; ++nt) {
                float p = __expf(S[nt][r] - mn);
                S[nt][r] = p;
                rs += p;
            }
            for (int off = 1; off < 16; off <<= 1) rs += __shfl_xor(rs, off, 64);
            l_i[r] = l_i[r] * alpha[r] + rs;
        }
        // P: C-layout -> LDS -> A-layout (per-wave slice, no barrier needed)
        for (int nt = 0; nt < 4; ++nt)
            for (int r = 0; r < 4; ++r)
                Ps[w][quad * 4 + r][nt * 16 + lrow] = f2b(S[nt][r]);
        for (int d = 0; d < 8; ++d)
            for (int r = 0; r < 4; ++r) accO[d][r] *= alpha[r];
        s16x8 pf0 = *(const s16x8*)&Ps[w][lrow][quad * 8];
        s16x8 pf1 = *(const s16x8*)&Ps[w][lrow][32 + quad * 8];
        for (int dt = 0; dt < 8; ++dt) {
            s16x8 vf0 = *(const s16x8*)&Vs[dt * 16 + lrow][quad * 8];
            s16x8 vf1 = *(const s16x8*)&Vs[dt * 16 + lrow][32 + quad * 8];
            accO[dt] = __builtin_amdgcn_mfma_f32_16x16x32_bf16(pf0, vf0, accO[dt], 0, 0, 0);
            accO[dt] = __builtin_amdgcn_mfma_f32_16x16x32_bf16(pf1, vf1, accO[dt], 0, 0, 0);
        }
        __syncthreads(); // all waves done reading Ks/Vs
        if (more) {
            store_tile();
            __syncthreads();
        }
    }
    // epilogue: o[b*SEQ + qr][h*HD + d]
    for (int dt = 0; dt < 8; ++dt)
        for (int r = 0; r < 4; ++r) {
            int qr = q0 + w * 16 + quad * 4 + r;
            size_t oi = ((size_t)(b * SEQ + qr)) * DM + h * HD + dt * 16 + lrow;
            o[oi] = f2b(accO[dt][r] / l_i[r]);
        }
}

extern "C" void kernel_launch(void* const* d_in, const int* in_sizes, int n_in,
                              void* d_out, int out_size, void* d_ws, size_t ws_size,
                              hipStream_t stream) {
    (void)in_sizes; (void)n_in; (void)out_size; (void)ws_size;
    const float* x  = (const float*)d_in[0];
    const float* fc = (const float*)d_in[1];
    const float* fs = (const float*)d_in[2];
    // d_in[3] = mask: exactly causal, applied analytically
    const float* wq = (const float*)d_in[4];
    const float* wk = (const float*)d_in[5];
    const float* wv = (const float*)d_in[6];
    const float* wo = (const float*)d_in[7];

    // workspace layout (bf16 elems), with stage-lifetime aliasing; total ~63 MB
    __hip_bfloat16* xb    = (__hip_bfloat16*)d_ws;            // [4096][2048]
    __hip_bfloat16* wqkvt = xb + (size_t)8388608;             // [3072][2048]
    __hip_bfloat16* wot   = wqkvt + (size_t)6291456;          // [2048][2048]
    __hip_bfloat16* qkv   = wot + (size_t)4194304;            // [4096][3072]
    __hip_bfloat16* qb    = xb;                               // [2][16][2048][128] (aliases xb)
    __hip_bfloat16* kb    = wqkvt;                            // [2][4][2048][128]  (aliases wqkvt)
    __hip_bfloat16* vtb   = wqkvt + (size_t)2097152;          // [2][4][128][2048]
    __hip_bfloat16* attno = qkv;                              // [4096][2048] (aliases qkv)

    // S1: casts + weight transposes
    cast_kernel<<<8192, 256, 0, stream>>>(x, xb, 8388608);
    transpose_cast<<<dim3(64, 64), dim3(32, 8), 0, stream>>>(wq, wqkvt, 2048, 2048);
    transpose_cast<<<dim3(16, 64), dim3(32, 8), 0, stream>>>(wk, wqkvt + (size_t)2048 * 2048, 2048, 512);
    transpose_cast<<<dim3(16, 64), dim3(32, 8), 0, stream>>>(wv, wqkvt + (size_t)2560 * 2048, 2048, 512);
    transpose_cast<<<dim3(64, 64), dim3(32, 8), 0, stream>>>(wo, wot, 2048, 2048);
    // S2: qkv = x @ [wq|wk|wv]
    gemm_bt<0><<<dim3(24, 32), 256, 0, stream>>>(xb, wqkvt, qkv, 4096, 3072, 2048);
    // S3: rope + reshape, V transpose
    rope_reshape<<<4096, 256, 0, stream>>>(qkv, fc, fs, qb, kb);
    vtrans<<<dim3(16, 8), 256, 0, stream>>>(qkv, vtb);
    // S4: causal GQA flash attention
    attn_kernel<<<dim3(32, 32), 256, 0, stream>>>(qb, kb, vtb, attno);
    // S5: out = attno @ wo (fp32 out)
    gemm_bt<1><<<dim3(16, 32), 256, 0, stream>>>(attno, wot, d_out, 4096, 2048, 2048);
}

// Round 5
// 393.247 us; speedup vs baseline: 1.4133x; 1.1572x over previous
//
#include <hip/hip_runtime.h>
#include <hip/hip_bf16.h>

#define SEQ 2048
#define DM 2048
#define NH 16
#define NKV 4
#define HD 128

typedef float f32x4 __attribute__((ext_vector_type(4)));
typedef short s16x8 __attribute__((ext_vector_type(8)));
typedef short s16x4 __attribute__((ext_vector_type(4)));

__device__ inline __hip_bfloat16 f2b(float f) { return __float2bfloat16(f); }
__device__ inline float b2f_us(unsigned short u) { return __uint_as_float(((unsigned)u) << 16); }
__device__ inline short f2b_s(float f) {
    __hip_bfloat16 h = __float2bfloat16(f);
    return *(short*)&h;
}

// ---------------- cast fp32 -> bf16 ----------------
__global__ void cast_kernel(const float* __restrict__ in, __hip_bfloat16* __restrict__ out, int n) {
    int i = (blockIdx.x * 256 + threadIdx.x) * 4;
    if (i < n) {
        float4 v = *(const float4*)(in + i);
        __hip_bfloat16 o4[4] = {f2b(v.x), f2b(v.y), f2b(v.z), f2b(v.w)};
        *(ushort4*)(out + i) = *(ushort4*)o4;
    }
}

// ---------------- transpose + cast: in[K][N] fp32 -> out[N][K] bf16 ----------------
__global__ void transpose_cast(const float* __restrict__ in, __hip_bfloat16* __restrict__ out,
                               int K, int N) {
    __shared__ float tile[32][33];
    int n0 = blockIdx.x * 32, k0 = blockIdx.y * 32;
    int tx = threadIdx.x, ty = threadIdx.y; // block (32,8)
    for (int r = ty; r < 32; r += 8)
        tile[r][tx] = in[(size_t)(k0 + r) * N + n0 + tx];
    __syncthreads();
    for (int r = ty; r < 32; r += 8)
        out[(size_t)(n0 + r) * K + k0 + tx] = f2b(tile[tx][r]);
}

// ---------------- GEMM: C[M][N] = A[M][Kd] * Bt[N][Kd]^T, bf16 in, fp32 acc ----------------
// R2-proven register-prefetch pipeline.
template <int OUT_F32>
__global__ __launch_bounds__(256, 2) void gemm_bt(
    const __hip_bfloat16* __restrict__ A,
    const __hip_bfloat16* __restrict__ Bt,
    void* __restrict__ Cp, int M, int N, int Kd) {
    __shared__ __hip_bfloat16 As[128][72]; // stride 144B: 16B-aligned rows, 2-way banks (free)
    __shared__ __hip_bfloat16 Bs[128][72];
    const int m0 = blockIdx.y * 128, n0 = blockIdx.x * 128;
    const int t = threadIdx.x;
    const int wv = t >> 6, lane = t & 63;
    const int wm = (wv >> 1) * 64, wn = (wv & 1) * 64;
    const int lrow = lane & 15, quad = lane >> 4;
    f32x4 acc[4][4];
    f32x4 z4 = {0.f, 0.f, 0.f, 0.f};
    for (int i = 0; i < 4; ++i)
        for (int j = 0; j < 4; ++j) acc[i][j] = z4;

    s16x8 ar[4], br[4];
    auto load_tile = [&](int k0) {
        for (int i = 0; i < 4; ++i) {
            int flat = (i * 256 + t) * 8;
            int row = flat >> 6, col = flat & 63;
            ar[i] = *(const s16x8*)(A + (size_t)(m0 + row) * Kd + k0 + col);
            br[i] = *(const s16x8*)(Bt + (size_t)(n0 + row) * Kd + k0 + col);
        }
    };
    auto store_tile = [&]() {
        for (int i = 0; i < 4; ++i) {
            int flat = (i * 256 + t) * 8;
            int row = flat >> 6, col = flat & 63;
            *(s16x8*)&As[row][col] = ar[i];
            *(s16x8*)&Bs[row][col] = br[i];
        }
    };

    load_tile(0);
    store_tile();
    __syncthreads();

    for (int k0 = 0; k0 < Kd; k0 += 64) {
        bool more = (k0 + 64) < Kd;
        if (more) load_tile(k0 + 64); // in flight across frag reads + MFMA
        s16x8 af[2][4], bf[2][4];
        for (int kk = 0; kk < 2; ++kk)
            for (int i = 0; i < 4; ++i) {
                af[kk][i] = *(const s16x8*)&As[wm + i * 16 + lrow][kk * 32 + quad * 8];
                bf[kk][i] = *(const s16x8*)&Bs[wn + i * 16 + lrow][kk * 32 + quad * 8];
            }
        for (int kk = 0; kk < 2; ++kk)
            for (int i = 0; i < 4; ++i)
                for (int j = 0; j < 4; ++j)
                    acc[i][j] = __builtin_amdgcn_mfma_f32_16x16x32_bf16(af[kk][i], bf[kk][j],
                                                                        acc[i][j], 0, 0, 0);
        __syncthreads();
        if (more) {
            store_tile();
            __syncthreads();
        }
    }
    // C layout: col = lane&15, row = quad*4 + reg  [guide §3, m89-verified]
    for (int i = 0; i < 4; ++i)
        for (int j = 0; j < 4; ++j)
            for (int r = 0; r < 4; ++r) {
                int m = m0 + wm + i * 16 + quad * 4 + r;
                int n = n0 + wn + j * 16 + lrow;
                if (OUT_F32)
                    ((float*)Cp)[(size_t)m * N + n] = acc[i][j][r];
                else
                    ((__hip_bfloat16*)Cp)[(size_t)m * N + n] = f2b(acc[i][j][r]);
            }
}

// ---------------- RoPE + reshape (q, k only), vectorized ----------------
__global__ void rope_reshape(const __hip_bfloat16* __restrict__ qkv,
                             const float* __restrict__ fcos, const float* __restrict__ fsin,
                             __hip_bfloat16* __restrict__ q, __hip_bfloat16* __restrict__ k) {
    int tok = blockIdx.x; // b*SEQ + s
    int b = tok >> 11, s = tok & 2047;
    const __hip_bfloat16* row = qkv + (size_t)tok * 3072;
    for (int it = threadIdx.x; it < 320; it += 256) { // 2560 elems / 8
        int col = it * 8;
        s16x8 v = *(const s16x8*)(row + col);
        int p0 = (col & 127) >> 1; // multiple of 4
        f32x4 c4 = *(const f32x4*)(fcos + s * 64 + p0);
        f32x4 s4 = *(const f32x4*)(fsin + s * 64 + p0);
        short outv[8];
        for (int p = 0; p < 4; ++p) {
            float x0 = b2f_us((unsigned short)v[2 * p]);
            float x1 = b2f_us((unsigned short)v[2 * p + 1]);
            outv[2 * p] = f2b_s(x0 * c4[p] - x1 * s4[p]);
            outv[2 * p + 1] = f2b_s(x0 * s4[p] + x1 * c4[p]);
        }
        int d = col & 127;
        if (col < 2048) {
            int h = col >> 7;
            *(s16x8*)(q + ((size_t)((b * NH + h) * SEQ + s)) * HD + d) = *(s16x8*)outv;
        } else {
            int h = (col - 2048) >> 7;
            *(s16x8*)(k + ((size_t)((b * NKV + h) * SEQ + s)) * HD + d) = *(s16x8*)outv;
        }
    }
}

// ---------------- V transpose via LDS: qkv v-cols -> vt[b][kv][d][s] ----------------
__global__ void vtrans(const __hip_bfloat16* __restrict__ qkv, __hip_bfloat16* __restrict__ vt) {
    __shared__ __hip_bfloat16 tile[128][136];
    int s0 = blockIdx.x * 128;
    int bh = blockIdx.y; // b*NKV + kvh
    int b = bh >> 2, kvh = bh & 3;
    int t = threadIdx.x;
    for (int i = 0; i < 8; ++i) {
        int flat = (i * 256 + t) * 8;
        int row = flat >> 7, col = flat & 127;
        *(s16x8*)&tile[row][col] =
            *(const s16x8*)(qkv + (size_t)(b * SEQ + s0 + row) * 3072 + 2560 + kvh * 128 + col);
    }
    __syncthreads();
    for (int i = 0; i < 8; ++i) {
        int dd = i * 16 + (t >> 4);
        int ss = (t & 15) * 8;
        __hip_bfloat16 tmp[8];
        for (int j = 0; j < 8; ++j) tmp[j] = tile[ss + j][dd];
        *(s16x8*)(vt + ((size_t)((b * NKV + kvh) * HD + dd)) * SEQ + s0 + ss) = *(s16x8*)tmp;
    }
}

// ---------------- causal flash attention (GQA), transposed-MFMA geometry ----------------
// S^T = K·Q^T (m=key, n=qrow); PV via A=V^T (m=d), B=P^T (n=qrow).
// DEFENSIVE softmax: true online max + direct sum. In this geometry each lane
// owns exactly ONE q-row (n=lane&15); row stats need only in-lane reduction
// over 16 values + shfl_xor(16) + shfl_xor(32). Guarantees l >= 1 (diagonal
// p == 1), alpha in [0,1], masked scores finite -> no NaN path.
__global__ __launch_bounds__(256, 3) void attn_kernel(
    const __hip_bfloat16* __restrict__ q, const __hip_bfloat16* __restrict__ k,
    const __hip_bfloat16* __restrict__ vt, __hip_bfloat16* __restrict__ o) {
    __shared__ __hip_bfloat16 Ks[64][136];  // keys x d
    __shared__ __hip_bfloat16 Vs[128][72];  // d x keys
    __shared__ __hip_bfloat16 Ps[4][16][72]; // per-wave: qrow x key

    const int bx = (gridDim.x - 1) - blockIdx.x; // heavy blocks dispatch first
    const int bh = blockIdx.y;
    const int b = bh >> 4, h = bh & 15;
    const int kvh = h >> 2;
    const int t = threadIdx.x;
    const int w = t >> 6, lane = t & 63;
    const int lrow = lane & 15, quad = lane >> 4;
    const int q0 = bx * 64;
    const int qrow = q0 + w * 16 + lrow; // this lane's ONE q row (n-dim)
    const float scale = 0.08838834764831845f;

    // Q fragments, B-operand role: n=qrow (lrow), k=d (quad*8+j)
    const __hip_bfloat16* qp = q + ((size_t)((b * NH + h) * SEQ + qrow)) * HD;
    s16x8 qf[4];
    for (int ks = 0; ks < 4; ++ks) qf[ks] = *(const s16x8*)(qp + ks * 32 + quad * 8);

    float m_i = -1e30f, l_i = 0.f;
    f32x4 accO[8];
    f32x4 z4 = {0.f, 0.f, 0.f, 0.f};
    for (int d = 0; d < 8; ++d) accO[d] = z4;

    const __hip_bfloat16* kbase = k + ((size_t)(b * NKV + kvh) * SEQ) * HD;
    const __hip_bfloat16* vbase = vt + ((size_t)(b * NKV + kvh) * HD) * SEQ;

    s16x8 kr[4], vr[4];
    auto load_tile = [&](int kt) {
        for (int i = 0; i < 4; ++i) {
            int flat = (i * 256 + t) * 8;
            kr[i] = *(const s16x8*)(kbase + (size_t)(kt * 64 + (flat >> 7)) * HD + (flat & 127));
            vr[i] = *(const s16x8*)(vbase + (size_t)(flat >> 6) * SEQ + kt * 64 + (flat & 63));
        }
    };
    auto store_tile = [&]() {
        for (int i = 0; i < 4; ++i) {
            int flat = (i * 256 + t) * 8;
            *(s16x8*)&Ks[flat >> 7][flat & 127] = kr[i];
            *(s16x8*)&Vs[flat >> 6][flat & 63] = vr[i];
        }
    };

    const int nkt = bx + 1;
    load_tile(0);
    store_tile();
    __syncthreads();

    for (int kt = 0; kt < nkt; ++kt) {
        bool more = (kt + 1) < nkt;
        if (more) load_tile(kt + 1);
        bool last = (kt == bx);

        // S^T tiles: lane holds keys kt*64 + nt*16 + quad*4 + (0..3) at its qrow
        float sv[4][4];
        for (int nt = 0; nt < 4; ++nt) {
            f32x4 sacc = z4;
            for (int ks = 0; ks < 4; ++ks) {
                s16x8 kf = *(const s16x8*)&Ks[nt * 16 + lrow][ks * 32 + quad * 8];
                sacc = __builtin_amdgcn_mfma_f32_16x16x32_bf16(kf, qf[ks], sacc, 0, 0, 0);
            }
            for (int r = 0; r < 4; ++r) {
                int key = kt * 64 + nt * 16 + quad * 4 + r;
                sv[nt][r] = (last && key > qrow) ? -1e30f : sacc[r] * scale;
            }
        }
        // row max: in-lane over 16, then across quads (lanes lrow, lrow+16, +32, +48)
        float mt = -1e30f;
        for (int nt = 0; nt < 4; ++nt)
            for (int r = 0; r < 4; ++r) mt = fmaxf(mt, sv[nt][r]);
        mt = fmaxf(mt, __shfl_xor(mt, 16, 64));
        mt = fmaxf(mt, __shfl_xor(mt, 32, 64));
        float mn = fmaxf(m_i, mt);
        float alpha = __expf(m_i - mn);
        m_i = mn;
        // p + row sum
        float rs = 0.f;
        for (int nt = 0; nt < 4; ++nt) {
            short ph[4];
            for (int r = 0; r < 4; ++r) {
                float p = __expf(sv[nt][r] - mn);
                rs += p;
                ph[r] = f2b_s(p);
            }
            *(s16x4*)&Ps[w][lrow][nt * 16 + quad * 4] = *(s16x4*)ph;
        }
        rs += __shfl_xor(rs, 16, 64);
        rs += __shfl_xor(rs, 32, 64);
        l_i = l_i * alpha + rs;
        // rescale O (single alpha: all accO elems belong to this lane's one qrow)
        for (int d = 0; d < 8; ++d)
            for (int r = 0; r < 4; ++r) accO[d][r] *= alpha;
        // P B-frags (n=qrow=lrow, k=key=quad*8+j), same-wave data
        s16x8 pf0 = *(const s16x8*)&Ps[w][lrow][quad * 8];
        s16x8 pf1 = *(const s16x8*)&Ps[w][lrow][32 + quad * 8];
        for (int dt = 0; dt < 8; ++dt) {
            s16x8 vf0 = *(const s16x8*)&Vs[dt * 16 + lrow][quad * 8];
            s16x8 vf1 = *(const s16x8*)&Vs[dt * 16 + lrow][32 + quad * 8];
            accO[dt] = __builtin_amdgcn_mfma_f32_16x16x32_bf16(vf0, pf0, accO[dt], 0, 0, 0);
            accO[dt] = __builtin_amdgcn_mfma_f32_16x16x32_bf16(vf1, pf1, accO[dt], 0, 0, 0);
        }

        __syncthreads();
        if (more) {
            store_tile();
            __syncthreads();
        }
    }
    // epilogue: accO[dt][r] = O^T[d = dt*16+quad*4+r][qrow]; l_i >= 1
    float inv = 1.0f / l_i;
    __hip_bfloat16* op = o + (size_t)(b * SEQ + qrow) * DM + h * HD;
    for (int dt = 0; dt < 8; ++dt) {
        short ov[4];
        for (int r = 0; r < 4; ++r) ov[r] = f2b_s(accO[dt][r] * inv);
        *(s16x4*)(op + dt * 16 + quad * 4) = *(s16x4*)ov;
    }
}

extern "C" void kernel_launch(void* const* d_in, const int* in_sizes, int n_in,
                              void* d_out, int out_size, void* d_ws, size_t ws_size,
                              hipStream_t stream) {
    (void)in_sizes; (void)n_in; (void)out_size; (void)ws_size;
    const float* x  = (const float*)d_in[0];
    const float* fc = (const float*)d_in[1];
    const float* fs = (const float*)d_in[2];
    // d_in[3] = mask: exactly causal, applied analytically
    const float* wq = (const float*)d_in[4];
    const float* wk = (const float*)d_in[5];
    const float* wv = (const float*)d_in[6];
    const float* wo = (const float*)d_in[7];

    __hip_bfloat16* xb    = (__hip_bfloat16*)d_ws;            // [4096][2048]
    __hip_bfloat16* wqkvt = xb + (size_t)8388608;             // [3072][2048]
    __hip_bfloat16* wot   = wqkvt + (size_t)6291456;          // [2048][2048]
    __hip_bfloat16* qkv   = wot + (size_t)4194304;            // [4096][3072]
    __hip_bfloat16* qb    = xb;                               // aliases xb
    __hip_bfloat16* kb    = wqkvt;                            // aliases wqkvt
    __hip_bfloat16* vtb   = wqkvt + (size_t)2097152;
    __hip_bfloat16* attno = qkv;                              // aliases qkv

    cast_kernel<<<8192, 256, 0, stream>>>(x, xb, 8388608);
    transpose_cast<<<dim3(64, 64), dim3(32, 8), 0, stream>>>(wq, wqkvt, 2048, 2048);
    transpose_cast<<<dim3(16, 64), dim3(32, 8), 0, stream>>>(wk, wqkvt + (size_t)2048 * 2048, 2048, 512);
    transpose_cast<<<dim3(16, 64), dim3(32, 8), 0, stream>>>(wv, wqkvt + (size_t)2560 * 2048, 2048, 512);
    transpose_cast<<<dim3(64, 64), dim3(32, 8), 0, stream>>>(wo, wot, 2048, 2048);
    gemm_bt<0><<<dim3(24, 32), 256, 0, stream>>>(xb, wqkvt, qkv, 4096, 3072, 2048);
    rope_reshape<<<4096, 256, 0, stream>>>(qkv, fc, fs, qb, kb);
    vtrans<<<dim3(16, 8), 256, 0, stream>>>(qkv, vtb);
    attn_kernel<<<dim3(32, 32), 256, 0, stream>>>(qb, kb, vtb, attno);
    gemm_bt<1><<<dim3(16, 32), 256, 0, stream>>>(attno, wot, d_out, 4096, 2048, 2048);
}

// Round 6
// 377.247 us; speedup vs baseline: 1.4732x; 1.0424x over previous
//
#include <hip/hip_runtime.h>
#include <hip/hip_bf16.h>

#define SEQ 2048
#define DM 2048
#define NH 16
#define NKV 4
#define HD 128

typedef float f32x4 __attribute__((ext_vector_type(4)));
typedef short s16x8 __attribute__((ext_vector_type(8)));
typedef short s16x4 __attribute__((ext_vector_type(4)));

__device__ inline __hip_bfloat16 f2b(float f) { return __float2bfloat16(f); }
__device__ inline float b2f_us(unsigned short u) { return __uint_as_float(((unsigned)u) << 16); }
__device__ inline short f2b_s(float f) {
    __hip_bfloat16 h = __float2bfloat16(f);
    return *(short*)&h;
}

// async global->LDS, 16B per lane; HW dest = wave-uniform base + lane*16.
// Callers pass per-lane ptrs that are exactly base + lane*16.
__device__ inline void gl_lds16(const void* g, void* l) {
    __builtin_amdgcn_global_load_lds((const __attribute__((address_space(1))) void*)g,
                                     (__attribute__((address_space(3))) void*)l, 16, 0, 0);
}

// ---------------- cast fp32 -> bf16 ----------------
__global__ void cast_kernel(const float* __restrict__ in, __hip_bfloat16* __restrict__ out, int n) {
    int i = (blockIdx.x * 256 + threadIdx.x) * 4;
    if (i < n) {
        float4 v = *(const float4*)(in + i);
        __hip_bfloat16 o4[4] = {f2b(v.x), f2b(v.y), f2b(v.z), f2b(v.w)};
        *(ushort4*)(out + i) = *(ushort4*)o4;
    }
}

// ---------------- transpose + cast: in[K][N] fp32 -> out[N][K] bf16 ----------------
__global__ void transpose_cast(const float* __restrict__ in, __hip_bfloat16* __restrict__ out,
                               int K, int N) {
    __shared__ float tile[32][33];
    int n0 = blockIdx.x * 32, k0 = blockIdx.y * 32;
    int tx = threadIdx.x, ty = threadIdx.y; // block (32,8)
    for (int r = ty; r < 32; r += 8)
        tile[r][tx] = in[(size_t)(k0 + r) * N + n0 + tx];
    __syncthreads();
    for (int r = ty; r < 32; r += 8)
        out[(size_t)(n0 + r) * K + k0 + tx] = f2b(tile[tx][r]);
}

// ---------------- GEMM: C[M][N] = A[M][Kd] * Bt[N][Kd]^T ----------------
// m97 structure: global_load_lds width-16 staging (no VGPR round-trip),
// unpadded LDS, XOR swizzle applied on the GATHER side: physical 16B slot
// (row, pb) holds logical block cb = pb ^ (row&7). Self-inverse; 8-lane
// groups read a permuted 128B row -> still fully coalesced.
template <int OUT_F32>
__global__ __launch_bounds__(256, 3) void gemm_bt(
    const __hip_bfloat16* __restrict__ A,
    const __hip_bfloat16* __restrict__ Bt,
    void* __restrict__ Cp, int M, int N, int Kd) {
    __shared__ __hip_bfloat16 As[128 * 64]; // [row][64], swizzled 16B slots
    __shared__ __hip_bfloat16 Bs[128 * 64];
    const int m0 = blockIdx.y * 128, n0 = blockIdx.x * 128;
    const int t = threadIdx.x;
    const int wv = t >> 6, lane = t & 63;
    const int wm = (wv >> 1) * 64, wn = (wv & 1) * 64;
    const int lrow = lane & 15, quad = lane >> 4;
    f32x4 acc[4][4];
    f32x4 z4 = {0.f, 0.f, 0.f, 0.f};
    for (int i = 0; i < 4; ++i)
        for (int j = 0; j < 4; ++j) acc[i][j] = z4;

    for (int k0 = 0; k0 < Kd; k0 += 64) {
        __syncthreads(); // previous iter's frag reads done before overwrite
        for (int i = 0; i < 4; ++i) {
            int flat = i * 256 + t;          // 16B slot id, = wave_base + lane
            int row = flat >> 3;
            int cb = (flat & 7) ^ (row & 7); // logical 16B-block for this physical slot
            gl_lds16(A + (size_t)(m0 + row) * Kd + k0 + cb * 8, &As[flat * 8]);
            gl_lds16(Bt + (size_t)(n0 + row) * Kd + k0 + cb * 8, &Bs[flat * 8]);
        }
        __syncthreads(); // barrier drains vmcnt -> LDS tile ready
        for (int kk = 0; kk < 2; ++kk) {
            s16x8 af[4], bf[4];
            for (int i = 0; i < 4; ++i) {
                int ra = wm + i * 16 + lrow;
                int rb = wn + i * 16 + lrow;
                int pba = ((kk * 4 + quad) ^ (ra & 7)) * 8;
                int pbb = ((kk * 4 + quad) ^ (rb & 7)) * 8;
                af[i] = *(const s16x8*)&As[ra * 64 + pba];
                bf[i] = *(const s16x8*)&Bs[rb * 64 + pbb];
            }
            for (int i = 0; i < 4; ++i)
                for (int j = 0; j < 4; ++j)
                    acc[i][j] = __builtin_amdgcn_mfma_f32_16x16x32_bf16(af[i], bf[j],
                                                                        acc[i][j], 0, 0, 0);
        }
    }
    // C layout: col = lane&15, row = quad*4 + reg  [guide §3, m89-verified]
    for (int i = 0; i < 4; ++i)
        for (int j = 0; j < 4; ++j)
            for (int r = 0; r < 4; ++r) {
                int m = m0 + wm + i * 16 + quad * 4 + r;
                int n = n0 + wn + j * 16 + lrow;
                if (OUT_F32)
                    ((float*)Cp)[(size_t)m * N + n] = acc[i][j][r];
                else
                    ((__hip_bfloat16*)Cp)[(size_t)m * N + n] = f2b(acc[i][j][r]);
            }
}

// ---------------- RoPE + reshape (q, k only), vectorized ----------------
__global__ void rope_reshape(const __hip_bfloat16* __restrict__ qkv,
                             const float* __restrict__ fcos, const float* __restrict__ fsin,
                             __hip_bfloat16* __restrict__ q, __hip_bfloat16* __restrict__ k) {
    int tok = blockIdx.x; // b*SEQ + s
    int b = tok >> 11, s = tok & 2047;
    const __hip_bfloat16* row = qkv + (size_t)tok * 3072;
    for (int it = threadIdx.x; it < 320; it += 256) { // 2560 elems / 8
        int col = it * 8;
        s16x8 v = *(const s16x8*)(row + col);
        int p0 = (col & 127) >> 1; // multiple of 4
        f32x4 c4 = *(const f32x4*)(fcos + s * 64 + p0);
        f32x4 s4 = *(const f32x4*)(fsin + s * 64 + p0);
        short outv[8];
        for (int p = 0; p < 4; ++p) {
            float x0 = b2f_us((unsigned short)v[2 * p]);
            float x1 = b2f_us((unsigned short)v[2 * p + 1]);
            outv[2 * p] = f2b_s(x0 * c4[p] - x1 * s4[p]);
            outv[2 * p + 1] = f2b_s(x0 * s4[p] + x1 * c4[p]);
        }
        int d = col & 127;
        if (col < 2048) {
            int h = col >> 7;
            *(s16x8*)(q + ((size_t)((b * NH + h) * SEQ + s)) * HD + d) = *(s16x8*)outv;
        } else {
            int h = (col - 2048) >> 7;
            *(s16x8*)(k + ((size_t)((b * NKV + h) * SEQ + s)) * HD + d) = *(s16x8*)outv;
        }
    }
}

// ---------------- V transpose via LDS: qkv v-cols -> vt[b][kv][d][s] ----------------
__global__ void vtrans(const __hip_bfloat16* __restrict__ qkv, __hip_bfloat16* __restrict__ vt) {
    __shared__ __hip_bfloat16 tile[128][136];
    int s0 = blockIdx.x * 128;
    int bh = blockIdx.y; // b*NKV + kvh
    int b = bh >> 2, kvh = bh & 3;
    int t = threadIdx.x;
    for (int i = 0; i < 8; ++i) {
        int flat = (i * 256 + t) * 8;
        int row = flat >> 7, col = flat & 127;
        *(s16x8*)&tile[row][col] =
            *(const s16x8*)(qkv + (size_t)(b * SEQ + s0 + row) * 3072 + 2560 + kvh * 128 + col);
    }
    __syncthreads();
    for (int i = 0; i < 8; ++i) {
        int dd = i * 16 + (t >> 4);
        int ss = (t & 15) * 8;
        __hip_bfloat16 tmp[8];
        for (int j = 0; j < 8; ++j) tmp[j] = tile[ss + j][dd];
        *(s16x8*)(vt + ((size_t)((b * NKV + kvh) * HD + dd)) * SEQ + s0 + ss) = *(s16x8*)tmp;
    }
}

// ---------------- causal flash attention (GQA), transposed-MFMA geometry ----------------
// R5-proven: S^T = K·Q^T (m=key, n=qrow); PV via A=V^T (m=d), B=P^T (n=qrow).
// Defensive online softmax: lane owns one q-row; 4 shuffles/step; l >= 1.
__global__ __launch_bounds__(256, 3) void attn_kernel(
    const __hip_bfloat16* __restrict__ q, const __hip_bfloat16* __restrict__ k,
    const __hip_bfloat16* __restrict__ vt, __hip_bfloat16* __restrict__ o) {
    __shared__ __hip_bfloat16 Ks[64][136];  // keys x d
    __shared__ __hip_bfloat16 Vs[128][72];  // d x keys
    __shared__ __hip_bfloat16 Ps[4][16][72]; // per-wave: qrow x key

    const int bx = (gridDim.x - 1) - blockIdx.x; // heavy blocks dispatch first
    const int bh = blockIdx.y;
    const int b = bh >> 4, h = bh & 15;
    const int kvh = h >> 2;
    const int t = threadIdx.x;
    const int w = t >> 6, lane = t & 63;
    const int lrow = lane & 15, quad = lane >> 4;
    const int q0 = bx * 64;
    const int qrow = q0 + w * 16 + lrow; // this lane's ONE q row (n-dim)
    const float scale = 0.08838834764831845f;

    // Q fragments, B-operand role: n=qrow (lrow), k=d (quad*8+j)
    const __hip_bfloat16* qp = q + ((size_t)((b * NH + h) * SEQ + qrow)) * HD;
    s16x8 qf[4];
    for (int ks = 0; ks < 4; ++ks) qf[ks] = *(const s16x8*)(qp + ks * 32 + quad * 8);

    float m_i = -1e30f, l_i = 0.f;
    f32x4 accO[8];
    f32x4 z4 = {0.f, 0.f, 0.f, 0.f};
    for (int d = 0; d < 8; ++d) accO[d] = z4;

    const __hip_bfloat16* kbase = k + ((size_t)(b * NKV + kvh) * SEQ) * HD;
    const __hip_bfloat16* vbase = vt + ((size_t)(b * NKV + kvh) * HD) * SEQ;

    s16x8 kr[4], vr[4];
    auto load_tile = [&](int kt) {
        for (int i = 0; i < 4; ++i) {
            int flat = (i * 256 + t) * 8;
            kr[i] = *(const s16x8*)(kbase + (size_t)(kt * 64 + (flat >> 7)) * HD + (flat & 127));
            vr[i] = *(const s16x8*)(vbase + (size_t)(flat >> 6) * SEQ + kt * 64 + (flat & 63));
        }
    };
    auto store_tile = [&]() {
        for (int i = 0; i < 4; ++i) {
            int flat = (i * 256 + t) * 8;
            *(s16x8*)&Ks[flat >> 7][flat & 127] = kr[i];
            *(s16x8*)&Vs[flat >> 6][flat & 63] = vr[i];
        }
    };

    const int nkt = bx + 1;
    load_tile(0);
    store_tile();
    __syncthreads();

    for (int kt = 0; kt < nkt; ++kt) {
        bool more = (kt + 1) < nkt;
        if (more) load_tile(kt + 1);
        bool last = (kt == bx);

        // S^T tiles: lane holds keys kt*64 + nt*16 + quad*4 + (0..3) at its qrow
        float sv[4][4];
        for (int nt = 0; nt < 4; ++nt) {
            f32x4 sacc = z4;
            for (int ks = 0; ks < 4; ++ks) {
                s16x8 kf = *(const s16x8*)&Ks[nt * 16 + lrow][ks * 32 + quad * 8];
                sacc = __builtin_amdgcn_mfma_f32_16x16x32_bf16(kf, qf[ks], sacc, 0, 0, 0);
            }
            for (int r = 0; r < 4; ++r) {
                int key = kt * 64 + nt * 16 + quad * 4 + r;
                sv[nt][r] = (last && key > qrow) ? -1e30f : sacc[r] * scale;
            }
        }
        // row max: in-lane over 16, then across quads (lanes lrow, lrow+16, +32, +48)
        float mt = -1e30f;
        for (int nt = 0; nt < 4; ++nt)
            for (int r = 0; r < 4; ++r) mt = fmaxf(mt, sv[nt][r]);
        mt = fmaxf(mt, __shfl_xor(mt, 16, 64));
        mt = fmaxf(mt, __shfl_xor(mt, 32, 64));
        float mn = fmaxf(m_i, mt);
        float alpha = __expf(m_i - mn);
        m_i = mn;
        // p + row sum
        float rs = 0.f;
        for (int nt = 0; nt < 4; ++nt) {
            short ph[4];
            for (int r = 0; r < 4; ++r) {
                float p = __expf(sv[nt][r] - mn);
                rs += p;
                ph[r] = f2b_s(p);
            }
            *(s16x4*)&Ps[w][lrow][nt * 16 + quad * 4] = *(s16x4*)ph;
        }
        rs += __shfl_xor(rs, 16, 64);
        rs += __shfl_xor(rs, 32, 64);
        l_i = l_i * alpha + rs;
        // rescale O (single alpha: all accO elems belong to this lane's one qrow)
        for (int d = 0; d < 8; ++d)
            for (int r = 0; r < 4; ++r) accO[d][r] *= alpha;
        // P B-frags (n=qrow=lrow, k=key=quad*8+j), same-wave data
        s16x8 pf0 = *(const s16x8*)&Ps[w][lrow][quad * 8];
        s16x8 pf1 = *(const s16x8*)&Ps[w][lrow][32 + quad * 8];
        for (int dt = 0; dt < 8; ++dt) {
            s16x8 vf0 = *(const s16x8*)&Vs[dt * 16 + lrow][quad * 8];
            s16x8 vf1 = *(const s16x8*)&Vs[dt * 16 + lrow][32 + quad * 8];
            accO[dt] = __builtin_amdgcn_mfma_f32_16x16x32_bf16(vf0, pf0, accO[dt], 0, 0, 0);
            accO[dt] = __builtin_amdgcn_mfma_f32_16x16x32_bf16(vf1, pf1, accO[dt], 0, 0, 0);
        }

        __syncthreads();
        if (more) {
            store_tile();
            __syncthreads();
        }
    }
    // epilogue: accO[dt][r] = O^T[d = dt*16+quad*4+r][qrow]; l_i >= 1
    float inv = 1.0f / l_i;
    __hip_bfloat16* op = o + (size_t)(b * SEQ + qrow) * DM + h * HD;
    for (int dt = 0; dt < 8; ++dt) {
        short ov[4];
        for (int r = 0; r < 4; ++r) ov[r] = f2b_s(accO[dt][r] * inv);
        *(s16x4*)(op + dt * 16 + quad * 4) = *(s16x4*)ov;
    }
}

extern "C" void kernel_launch(void* const* d_in, const int* in_sizes, int n_in,
                              void* d_out, int out_size, void* d_ws, size_t ws_size,
                              hipStream_t stream) {
    (void)in_sizes; (void)n_in; (void)out_size; (void)ws_size;
    const float* x  = (const float*)d_in[0];
    const float* fc = (const float*)d_in[1];
    const float* fs = (const float*)d_in[2];
    // d_in[3] = mask: exactly causal, applied analytically
    const float* wq = (const float*)d_in[4];
    const float* wk = (const float*)d_in[5];
    const float* wv = (const float*)d_in[6];
    const float* wo = (const float*)d_in[7];

    __hip_bfloat16* xb    = (__hip_bfloat16*)d_ws;            // [4096][2048]
    __hip_bfloat16* wqkvt = xb + (size_t)8388608;             // [3072][2048]
    __hip_bfloat16* wot   = wqkvt + (size_t)6291456;          // [2048][2048]
    __hip_bfloat16* qkv   = wot + (size_t)4194304;            // [4096][3072]
    __hip_bfloat16* qb    = xb;                               // aliases xb
    __hip_bfloat16* kb    = wqkvt;                            // aliases wqkvt
    __hip_bfloat16* vtb   = wqkvt + (size_t)2097152;
    __hip_bfloat16* attno = qkv;                              // aliases qkv

    cast_kernel<<<8192, 256, 0, stream>>>(x, xb, 8388608);
    transpose_cast<<<dim3(64, 64), dim3(32, 8), 0, stream>>>(wq, wqkvt, 2048, 2048);
    transpose_cast<<<dim3(16, 64), dim3(32, 8), 0, stream>>>(wk, wqkvt + (size_t)2048 * 2048, 2048, 512);
    transpose_cast<<<dim3(16, 64), dim3(32, 8), 0, stream>>>(wv, wqkvt + (size_t)2560 * 2048, 2048, 512);
    transpose_cast<<<dim3(64, 64), dim3(32, 8), 0, stream>>>(wo, wot, 2048, 2048);
    gemm_bt<0><<<dim3(24, 32), 256, 0, stream>>>(xb, wqkvt, qkv, 4096, 3072, 2048);
    rope_reshape<<<4096, 256, 0, stream>>>(qkv, fc, fs, qb, kb);
    vtrans<<<dim3(16, 8), 256, 0, stream>>>(qkv, vtb);
    attn_kernel<<<dim3(32, 32), 256, 0, stream>>>(qb, kb, vtb, attno);
    gemm_bt<1><<<dim3(16, 32), 256, 0, stream>>>(attno, wot, d_out, 4096, 2048, 2048);
}

// Round 7
// 358.982 us; speedup vs baseline: 1.5482x; 1.0509x over previous
//
#include <hip/hip_runtime.h>
#include <hip/hip_bf16.h>

#define SEQ 2048
#define DM 2048
#define NH 16
#define NKV 4
#define HD 128

typedef float f32x4 __attribute__((ext_vector_type(4)));
typedef short s16x8 __attribute__((ext_vector_type(8)));
typedef short s16x4 __attribute__((ext_vector_type(4)));

__device__ inline __hip_bfloat16 f2b(float f) { return __float2bfloat16(f); }
__device__ inline float b2f_us(unsigned short u) { return __uint_as_float(((unsigned)u) << 16); }
__device__ inline short f2b_s(float f) {
    __hip_bfloat16 h = __float2bfloat16(f);
    return *(short*)&h;
}

// async global->LDS, 16B per lane; HW dest = wave-uniform base + lane*16.
__device__ inline void gl_lds16(const void* g, void* l) {
    __builtin_amdgcn_global_load_lds((const __attribute__((address_space(1))) void*)g,
                                     (__attribute__((address_space(3))) void*)l, 16, 0, 0);
}

// ---------------- cast fp32 -> bf16 ----------------
__global__ void cast_kernel(const float* __restrict__ in, __hip_bfloat16* __restrict__ out, int n) {
    int i = (blockIdx.x * 256 + threadIdx.x) * 4;
    if (i < n) {
        float4 v = *(const float4*)(in + i);
        __hip_bfloat16 o4[4] = {f2b(v.x), f2b(v.y), f2b(v.z), f2b(v.w)};
        *(ushort4*)(out + i) = *(ushort4*)o4;
    }
}

// ---------------- transpose + cast: in[K][N] fp32 -> out[N][K] bf16 ----------------
__global__ void transpose_cast(const float* __restrict__ in, __hip_bfloat16* __restrict__ out,
                               int K, int N) {
    __shared__ float tile[32][33];
    int n0 = blockIdx.x * 32, k0 = blockIdx.y * 32;
    int tx = threadIdx.x, ty = threadIdx.y; // block (32,8)
    for (int r = ty; r < 32; r += 8)
        tile[r][tx] = in[(size_t)(k0 + r) * N + n0 + tx];
    __syncthreads();
    for (int r = ty; r < 32; r += 8)
        out[(size_t)(n0 + r) * K + k0 + tx] = f2b(tile[tx][r]);
}

// ---------------- GEMM: C[M][N] = A[M][Kd] * Bt[N][Kd]^T ----------------
// m97 structure + GROUP_M=8 grouped supertile swizzle: concurrent blocks
// cluster into 8-m-row panels so B-tiles are reused within L2 instead of
// streaming all of B per m-row sweep.
template <int OUT_F32>
__global__ __launch_bounds__(256, 3) void gemm_bt(
    const __hip_bfloat16* __restrict__ A,
    const __hip_bfloat16* __restrict__ Bt,
    void* __restrict__ Cp, int M, int N, int Kd) {
    __shared__ __hip_bfloat16 As[128 * 64]; // [row][64], swizzled 16B slots
    __shared__ __hip_bfloat16 Bs[128 * 64];
    // grouped swizzle
    const int nx = gridDim.x, ny = gridDim.y;
    const int pid = blockIdx.y * nx + blockIdx.x;
    const int GM = 8;
    const int grp = pid / (GM * nx);
    const int first = grp * GM;
    const int gsz = (ny - first < GM) ? (ny - first) : GM;
    const int mt = first + (pid % gsz);
    const int ntile = (pid % (GM * nx)) / gsz;
    const int m0 = mt * 128, n0 = ntile * 128;

    const int t = threadIdx.x;
    const int wv = t >> 6, lane = t & 63;
    const int wm = (wv >> 1) * 64, wn = (wv & 1) * 64;
    const int lrow = lane & 15, quad = lane >> 4;
    f32x4 acc[4][4];
    f32x4 z4 = {0.f, 0.f, 0.f, 0.f};
    for (int i = 0; i < 4; ++i)
        for (int j = 0; j < 4; ++j) acc[i][j] = z4;

    for (int k0 = 0; k0 < Kd; k0 += 64) {
        __syncthreads(); // previous iter's frag reads done before overwrite
        for (int i = 0; i < 4; ++i) {
            int flat = i * 256 + t;          // 16B slot id
            int row = flat >> 3;
            int cb = (flat & 7) ^ (row & 7); // logical 16B-block for this slot
            gl_lds16(A + (size_t)(m0 + row) * Kd + k0 + cb * 8, &As[flat * 8]);
            gl_lds16(Bt + (size_t)(n0 + row) * Kd + k0 + cb * 8, &Bs[flat * 8]);
        }
        __syncthreads(); // barrier drains vmcnt -> LDS tile ready
        for (int kk = 0; kk < 2; ++kk) {
            s16x8 af[4], bf[4];
            for (int i = 0; i < 4; ++i) {
                int ra = wm + i * 16 + lrow;
                int rb = wn + i * 16 + lrow;
                int pba = ((kk * 4 + quad) ^ (ra & 7)) * 8;
                int pbb = ((kk * 4 + quad) ^ (rb & 7)) * 8;
                af[i] = *(const s16x8*)&As[ra * 64 + pba];
                bf[i] = *(const s16x8*)&Bs[rb * 64 + pbb];
            }
            for (int i = 0; i < 4; ++i)
                for (int j = 0; j < 4; ++j)
                    acc[i][j] = __builtin_amdgcn_mfma_f32_16x16x32_bf16(af[i], bf[j],
                                                                        acc[i][j], 0, 0, 0);
        }
    }
    // C layout: col = lane&15, row = quad*4 + reg
    for (int i = 0; i < 4; ++i)
        for (int j = 0; j < 4; ++j)
            for (int r = 0; r < 4; ++r) {
                int m = m0 + wm + i * 16 + quad * 4 + r;
                int n = n0 + wn + j * 16 + lrow;
                if (OUT_F32)
                    ((float*)Cp)[(size_t)m * N + n] = acc[i][j][r];
                else
                    ((__hip_bfloat16*)Cp)[(size_t)m * N + n] = f2b(acc[i][j][r]);
            }
}

// ---------------- RoPE + reshape (q, k only), vectorized ----------------
__global__ void rope_reshape(const __hip_bfloat16* __restrict__ qkv,
                             const float* __restrict__ fcos, const float* __restrict__ fsin,
                             __hip_bfloat16* __restrict__ q, __hip_bfloat16* __restrict__ k) {
    int tok = blockIdx.x; // b*SEQ + s
    int b = tok >> 11, s = tok & 2047;
    const __hip_bfloat16* row = qkv + (size_t)tok * 3072;
    for (int it = threadIdx.x; it < 320; it += 256) { // 2560 elems / 8
        int col = it * 8;
        s16x8 v = *(const s16x8*)(row + col);
        int p0 = (col & 127) >> 1; // multiple of 4
        f32x4 c4 = *(const f32x4*)(fcos + s * 64 + p0);
        f32x4 s4 = *(const f32x4*)(fsin + s * 64 + p0);
        short outv[8];
        for (int p = 0; p < 4; ++p) {
            float x0 = b2f_us((unsigned short)v[2 * p]);
            float x1 = b2f_us((unsigned short)v[2 * p + 1]);
            outv[2 * p] = f2b_s(x0 * c4[p] - x1 * s4[p]);
            outv[2 * p + 1] = f2b_s(x0 * s4[p] + x1 * c4[p]);
        }
        int d = col & 127;
        if (col < 2048) {
            int h = col >> 7;
            *(s16x8*)(q + ((size_t)((b * NH + h) * SEQ + s)) * HD + d) = *(s16x8*)outv;
        } else {
            int h = (col - 2048) >> 7;
            *(s16x8*)(k + ((size_t)((b * NKV + h) * SEQ + s)) * HD + d) = *(s16x8*)outv;
        }
    }
}

// ---------------- V transpose via LDS: qkv v-cols -> vt[b][kv][d][s] ----------------
__global__ void vtrans(const __hip_bfloat16* __restrict__ qkv, __hip_bfloat16* __restrict__ vt) {
    __shared__ __hip_bfloat16 tile[128][136];
    int s0 = blockIdx.x * 128;
    int bh = blockIdx.y; // b*NKV + kvh
    int b = bh >> 2, kvh = bh & 3;
    int t = threadIdx.x;
    for (int i = 0; i < 8; ++i) {
        int flat = (i * 256 + t) * 8;
        int row = flat >> 7, col = flat & 127;
        *(s16x8*)&tile[row][col] =
            *(const s16x8*)(qkv + (size_t)(b * SEQ + s0 + row) * 3072 + 2560 + kvh * 128 + col);
    }
    __syncthreads();
    for (int i = 0; i < 8; ++i) {
        int dd = i * 16 + (t >> 4);
        int ss = (t & 15) * 8;
        __hip_bfloat16 tmp[8];
        for (int j = 0; j < 8; ++j) tmp[j] = tile[ss + j][dd];
        *(s16x8*)(vt + ((size_t)((b * NKV + kvh) * HD + dd)) * SEQ + s0 + ss) = *(s16x8*)tmp;
    }
}

// ---------------- causal flash attention (GQA) ----------------
// R5-proven transposed geometry, scaled to 128 q-rows per block (512 thr,
// 8 waves): same K/V staging feeds 2x MFMA, halving per-step overhead and
// K/V L2 re-reads. Waves fully above the diagonal skip compute (wave-uniform).
__global__ __launch_bounds__(512, 4) void attn_kernel(
    const __hip_bfloat16* __restrict__ q, const __hip_bfloat16* __restrict__ k,
    const __hip_bfloat16* __restrict__ vt, __hip_bfloat16* __restrict__ o) {
    __shared__ __hip_bfloat16 Ks[64][136];   // keys x d
    __shared__ __hip_bfloat16 Vs[128][72];   // d x keys
    __shared__ __hip_bfloat16 Ps[8][16][72]; // per-wave: qrow x key

    const int bx = (gridDim.x - 1) - blockIdx.x; // heavy blocks dispatch first
    const int bh = blockIdx.y;
    const int b = bh >> 4, h = bh & 15;
    const int kvh = h >> 2;
    const int t = threadIdx.x;
    const int w = t >> 6, lane = t & 63;
    const int lrow = lane & 15, quad = lane >> 4;
    const int q0 = bx * 128;
    const int qrow = q0 + w * 16 + lrow; // this lane's ONE q row (n-dim)
    const float scale = 0.08838834764831845f;

    // Q fragments, B-operand role: n=qrow (lrow), k=d (quad*8+j)
    const __hip_bfloat16* qp = q + ((size_t)((b * NH + h) * SEQ + qrow)) * HD;
    s16x8 qf[4];
    for (int ks = 0; ks < 4; ++ks) qf[ks] = *(const s16x8*)(qp + ks * 32 + quad * 8);

    float m_i = -1e30f, l_i = 0.f;
    f32x4 accO[8];
    f32x4 z4 = {0.f, 0.f, 0.f, 0.f};
    for (int d = 0; d < 8; ++d) accO[d] = z4;

    const __hip_bfloat16* kbase = k + ((size_t)(b * NKV + kvh) * SEQ) * HD;
    const __hip_bfloat16* vbase = vt + ((size_t)(b * NKV + kvh) * HD) * SEQ;

    s16x8 kr[2], vr[2];
    auto load_tile = [&](int kt) {
        for (int i = 0; i < 2; ++i) {
            int flat = (i * 512 + t) * 8;
            kr[i] = *(const s16x8*)(kbase + (size_t)(kt * 64 + (flat >> 7)) * HD + (flat & 127));
            vr[i] = *(const s16x8*)(vbase + (size_t)(flat >> 6) * SEQ + kt * 64 + (flat & 63));
        }
    };
    auto store_tile = [&]() {
        for (int i = 0; i < 2; ++i) {
            int flat = (i * 512 + t) * 8;
            *(s16x8*)&Ks[flat >> 7][flat & 127] = kr[i];
            *(s16x8*)&Vs[flat >> 6][flat & 63] = vr[i];
        }
    };

    const int nkt = 2 * bx + 2; // keys [0, q0+128)
    load_tile(0);
    store_tile();
    __syncthreads();

    for (int kt = 0; kt < nkt; ++kt) {
        bool more = (kt + 1) < nkt;
        if (more) load_tile(kt + 1);
        // wave-uniform skip: this wave's rows [q0+w*16, q0+w*16+16) all above diag?
        bool wave_active = (kt * 64 <= q0 + w * 16 + 15);
        bool mtile = (kt >= 2 * bx); // tile may touch the diagonal

        if (wave_active) {
            // S^T tiles: lane holds keys kt*64 + nt*16 + quad*4 + (0..3) at its qrow
            float sv[4][4];
            for (int nt = 0; nt < 4; ++nt) {
                f32x4 sacc = z4;
                for (int ks = 0; ks < 4; ++ks) {
                    s16x8 kf = *(const s16x8*)&Ks[nt * 16 + lrow][ks * 32 + quad * 8];
                    sacc = __builtin_amdgcn_mfma_f32_16x16x32_bf16(kf, qf[ks], sacc, 0, 0, 0);
                }
                for (int r = 0; r < 4; ++r) {
                    int key = kt * 64 + nt * 16 + quad * 4 + r;
                    sv[nt][r] = (mtile && key > qrow) ? -1e30f : sacc[r] * scale;
                }
            }
            // row max: in-lane over 16, then across quads
            float mt2 = -1e30f;
            for (int nt = 0; nt < 4; ++nt)
                for (int r = 0; r < 4; ++r) mt2 = fmaxf(mt2, sv[nt][r]);
            mt2 = fmaxf(mt2, __shfl_xor(mt2, 16, 64));
            mt2 = fmaxf(mt2, __shfl_xor(mt2, 32, 64));
            float mn = fmaxf(m_i, mt2);
            float alpha = __expf(m_i - mn);
            m_i = mn;
            float rs = 0.f;
            for (int nt = 0; nt < 4; ++nt) {
                short ph[4];
                for (int r = 0; r < 4; ++r) {
                    float p = __expf(sv[nt][r] - mn);
                    rs += p;
                    ph[r] = f2b_s(p);
                }
                *(s16x4*)&Ps[w][lrow][nt * 16 + quad * 4] = *(s16x4*)ph;
            }
            rs += __shfl_xor(rs, 16, 64);
            rs += __shfl_xor(rs, 32, 64);
            l_i = l_i * alpha + rs;
            for (int d = 0; d < 8; ++d)
                for (int r = 0; r < 4; ++r) accO[d][r] *= alpha;
            // P B-frags (n=qrow=lrow, k=key=quad*8+j), same-wave data
            s16x8 pf0 = *(const s16x8*)&Ps[w][lrow][quad * 8];
            s16x8 pf1 = *(const s16x8*)&Ps[w][lrow][32 + quad * 8];
            for (int dt = 0; dt < 8; ++dt) {
                s16x8 vf0 = *(const s16x8*)&Vs[dt * 16 + lrow][quad * 8];
                s16x8 vf1 = *(const s16x8*)&Vs[dt * 16 + lrow][32 + quad * 8];
                accO[dt] = __builtin_amdgcn_mfma_f32_16x16x32_bf16(vf0, pf0, accO[dt], 0, 0, 0);
                accO[dt] = __builtin_amdgcn_mfma_f32_16x16x32_bf16(vf1, pf1, accO[dt], 0, 0, 0);
            }
        }

        __syncthreads();
        if (more) {
            store_tile();
            __syncthreads();
        }
    }
    // epilogue: accO[dt][r] = O^T[d = dt*16+quad*4+r][qrow]; l_i >= 1 (diagonal p=1)
    float inv = 1.0f / l_i;
    __hip_bfloat16* op = o + (size_t)(b * SEQ + qrow) * DM + h * HD;
    for (int dt = 0; dt < 8; ++dt) {
        short ov[4];
        for (int r = 0; r < 4; ++r) ov[r] = f2b_s(accO[dt][r] * inv);
        *(s16x4*)(op + dt * 16 + quad * 4) = *(s16x4*)ov;
    }
}

extern "C" void kernel_launch(void* const* d_in, const int* in_sizes, int n_in,
                              void* d_out, int out_size, void* d_ws, size_t ws_size,
                              hipStream_t stream) {
    (void)in_sizes; (void)n_in; (void)out_size; (void)ws_size;
    const float* x  = (const float*)d_in[0];
    const float* fc = (const float*)d_in[1];
    const float* fs = (const float*)d_in[2];
    // d_in[3] = mask: exactly causal, applied analytically
    const float* wq = (const float*)d_in[4];
    const float* wk = (const float*)d_in[5];
    const float* wv = (const float*)d_in[6];
    const float* wo = (const float*)d_in[7];

    __hip_bfloat16* xb    = (__hip_bfloat16*)d_ws;            // [4096][2048]
    __hip_bfloat16* wqkvt = xb + (size_t)8388608;             // [3072][2048]
    __hip_bfloat16* wot   = wqkvt + (size_t)6291456;          // [2048][2048]
    __hip_bfloat16* qkv   = wot + (size_t)4194304;            // [4096][3072]
    __hip_bfloat16* qb    = xb;                               // aliases xb
    __hip_bfloat16* kb    = wqkvt;                            // aliases wqkvt
    __hip_bfloat16* vtb   = wqkvt + (size_t)2097152;
    __hip_bfloat16* attno = qkv;                              // aliases qkv

    cast_kernel<<<8192, 256, 0, stream>>>(x, xb, 8388608);
    transpose_cast<<<dim3(64, 64), dim3(32, 8), 0, stream>>>(wq, wqkvt, 2048, 2048);
    transpose_cast<<<dim3(16, 64), dim3(32, 8), 0, stream>>>(wk, wqkvt + (size_t)2048 * 2048, 2048, 512);
    transpose_cast<<<dim3(16, 64), dim3(32, 8), 0, stream>>>(wv, wqkvt + (size_t)2560 * 2048, 2048, 512);
    transpose_cast<<<dim3(64, 64), dim3(32, 8), 0, stream>>>(wo, wot, 2048, 2048);
    gemm_bt<0><<<dim3(24, 32), 256, 0, stream>>>(xb, wqkvt, qkv, 4096, 3072, 2048);
    rope_reshape<<<4096, 256, 0, stream>>>(qkv, fc, fs, qb, kb);
    vtrans<<<dim3(16, 8), 256, 0, stream>>>(qkv, vtb);
    attn_kernel<<<dim3(16, 32), 512, 0, stream>>>(qb, kb, vtb, attno);
    gemm_bt<1><<<dim3(16, 32), 256, 0, stream>>>(attno, wot, d_out, 4096, 2048, 2048);
}

// Round 8
// 331.772 us; speedup vs baseline: 1.6752x; 1.0820x over previous
//
#include <hip/hip_runtime.h>
#include <hip/hip_bf16.h>

#define SEQ 2048
#define DM 2048
#define NH 16
#define NKV 4
#define HD 128

typedef float f32x4 __attribute__((ext_vector_type(4)));
typedef short s16x8 __attribute__((ext_vector_type(8)));
typedef short s16x4 __attribute__((ext_vector_type(4)));

__device__ inline __hip_bfloat16 f2b(float f) { return __float2bfloat16(f); }
__device__ inline float b2f_us(unsigned short u) { return __uint_as_float(((unsigned)u) << 16); }
__device__ inline short f2b_s(float f) {
    __hip_bfloat16 h = __float2bfloat16(f);
    return *(short*)&h;
}

// async global->LDS, 16B per lane; HW dest = wave-uniform base + lane*16.
__device__ inline void gl_lds16(const void* g, void* l) {
    __builtin_amdgcn_global_load_lds((const __attribute__((address_space(1))) void*)g,
                                     (__attribute__((address_space(3))) void*)l, 16, 0, 0);
}

// ---------------- cast fp32 -> bf16 ----------------
__global__ void cast_kernel(const float* __restrict__ in, __hip_bfloat16* __restrict__ out, int n) {
    int i = (blockIdx.x * 256 + threadIdx.x) * 4;
    if (i < n) {
        float4 v = *(const float4*)(in + i);
        __hip_bfloat16 o4[4] = {f2b(v.x), f2b(v.y), f2b(v.z), f2b(v.w)};
        *(ushort4*)(out + i) = *(ushort4*)o4;
    }
}

// ---------------- transpose + cast: in[K][N] fp32 -> out[N][K] bf16 ----------------
__global__ void transpose_cast(const float* __restrict__ in, __hip_bfloat16* __restrict__ out,
                               int K, int N) {
    __shared__ float tile[32][33];
    int n0 = blockIdx.x * 32, k0 = blockIdx.y * 32;
    int tx = threadIdx.x, ty = threadIdx.y; // block (32,8)
    for (int r = ty; r < 32; r += 8)
        tile[r][tx] = in[(size_t)(k0 + r) * N + n0 + tx];
    __syncthreads();
    for (int r = ty; r < 32; r += 8)
        out[(size_t)(n0 + r) * K + k0 + tx] = f2b(tile[tx][r]);
}

// ---------------- GEMM: C[M][N] = A[M][Kd] * Bt[N][Kd]^T ----------------
// m97 structure + GROUP_M=8 grouped supertile swizzle.
template <int OUT_F32>
__global__ __launch_bounds__(256, 3) void gemm_bt(
    const __hip_bfloat16* __restrict__ A,
    const __hip_bfloat16* __restrict__ Bt,
    void* __restrict__ Cp, int M, int N, int Kd) {
    __shared__ __hip_bfloat16 As[128 * 64]; // [row][64], swizzled 16B slots
    __shared__ __hip_bfloat16 Bs[128 * 64];
    const int nx = gridDim.x, ny = gridDim.y;
    const int pid = blockIdx.y * nx + blockIdx.x;
    const int GM = 8;
    const int grp = pid / (GM * nx);
    const int first = grp * GM;
    const int gsz = (ny - first < GM) ? (ny - first) : GM;
    const int mt = first + (pid % gsz);
    const int ntile = (pid % (GM * nx)) / gsz;
    const int m0 = mt * 128, n0 = ntile * 128;

    const int t = threadIdx.x;
    const int wv = t >> 6, lane = t & 63;
    const int wm = (wv >> 1) * 64, wn = (wv & 1) * 64;
    const int lrow = lane & 15, quad = lane >> 4;
    f32x4 acc[4][4];
    f32x4 z4 = {0.f, 0.f, 0.f, 0.f};
    for (int i = 0; i < 4; ++i)
        for (int j = 0; j < 4; ++j) acc[i][j] = z4;

    for (int k0 = 0; k0 < Kd; k0 += 64) {
        __syncthreads();
        for (int i = 0; i < 4; ++i) {
            int flat = i * 256 + t;          // 16B slot id
            int row = flat >> 3;
            int cb = (flat & 7) ^ (row & 7); // logical 16B-block for this slot
            gl_lds16(A + (size_t)(m0 + row) * Kd + k0 + cb * 8, &As[flat * 8]);
            gl_lds16(Bt + (size_t)(n0 + row) * Kd + k0 + cb * 8, &Bs[flat * 8]);
        }
        __syncthreads();
        for (int kk = 0; kk < 2; ++kk) {
            s16x8 af[4], bf[4];
            for (int i = 0; i < 4; ++i) {
                int ra = wm + i * 16 + lrow;
                int rb = wn + i * 16 + lrow;
                int pba = ((kk * 4 + quad) ^ (ra & 7)) * 8;
                int pbb = ((kk * 4 + quad) ^ (rb & 7)) * 8;
                af[i] = *(const s16x8*)&As[ra * 64 + pba];
                bf[i] = *(const s16x8*)&Bs[rb * 64 + pbb];
            }
            for (int i = 0; i < 4; ++i)
                for (int j = 0; j < 4; ++j)
                    acc[i][j] = __builtin_amdgcn_mfma_f32_16x16x32_bf16(af[i], bf[j],
                                                                        acc[i][j], 0, 0, 0);
        }
    }
    for (int i = 0; i < 4; ++i)
        for (int j = 0; j < 4; ++j)
            for (int r = 0; r < 4; ++r) {
                int m = m0 + wm + i * 16 + quad * 4 + r;
                int n = n0 + wn + j * 16 + lrow;
                if (OUT_F32)
                    ((float*)Cp)[(size_t)m * N + n] = acc[i][j][r];
                else
                    ((__hip_bfloat16*)Cp)[(size_t)m * N + n] = f2b(acc[i][j][r]);
            }
}

// ---------------- RoPE + reshape (q, k only), vectorized ----------------
__global__ void rope_reshape(const __hip_bfloat16* __restrict__ qkv,
                             const float* __restrict__ fcos, const float* __restrict__ fsin,
                             __hip_bfloat16* __restrict__ q, __hip_bfloat16* __restrict__ k) {
    int tok = blockIdx.x; // b*SEQ + s
    int b = tok >> 11, s = tok & 2047;
    const __hip_bfloat16* row = qkv + (size_t)tok * 3072;
    for (int it = threadIdx.x; it < 320; it += 256) { // 2560 elems / 8
        int col = it * 8;
        s16x8 v = *(const s16x8*)(row + col);
        int p0 = (col & 127) >> 1;
        f32x4 c4 = *(const f32x4*)(fcos + s * 64 + p0);
        f32x4 s4 = *(const f32x4*)(fsin + s * 64 + p0);
        short outv[8];
        for (int p = 0; p < 4; ++p) {
            float x0 = b2f_us((unsigned short)v[2 * p]);
            float x1 = b2f_us((unsigned short)v[2 * p + 1]);
            outv[2 * p] = f2b_s(x0 * c4[p] - x1 * s4[p]);
            outv[2 * p + 1] = f2b_s(x0 * s4[p] + x1 * c4[p]);
        }
        int d = col & 127;
        if (col < 2048) {
            int h = col >> 7;
            *(s16x8*)(q + ((size_t)((b * NH + h) * SEQ + s)) * HD + d) = *(s16x8*)outv;
        } else {
            int h = (col - 2048) >> 7;
            *(s16x8*)(k + ((size_t)((b * NKV + h) * SEQ + s)) * HD + d) = *(s16x8*)outv;
        }
    }
}

// ---------------- V transpose via LDS: qkv v-cols -> vt[b][kv][d][s] ----------------
__global__ void vtrans(const __hip_bfloat16* __restrict__ qkv, __hip_bfloat16* __restrict__ vt) {
    __shared__ __hip_bfloat16 tile[128][136];
    int s0 = blockIdx.x * 128;
    int bh = blockIdx.y; // b*NKV + kvh
    int b = bh >> 2, kvh = bh & 3;
    int t = threadIdx.x;
    for (int i = 0; i < 8; ++i) {
        int flat = (i * 256 + t) * 8;
        int row = flat >> 7, col = flat & 127;
        *(s16x8*)&tile[row][col] =
            *(const s16x8*)(qkv + (size_t)(b * SEQ + s0 + row) * 3072 + 2560 + kvh * 128 + col);
    }
    __syncthreads();
    for (int i = 0; i < 8; ++i) {
        int dd = i * 16 + (t >> 4);
        int ss = (t & 15) * 8;
        __hip_bfloat16 tmp[8];
        for (int j = 0; j < 8; ++j) tmp[j] = tile[ss + j][dd];
        *(s16x8*)(vt + ((size_t)((b * NKV + kvh) * HD + dd)) * SEQ + s0 + ss) = *(s16x8*)tmp;
    }
}

// ---------------- causal flash attention (GQA), 128 q-rows / 512 threads ----------------
// R7 structure. NEW: anti-correlated q-tile mapping. Dispatch is x-fastest, so
// blocks d and d+256 co-reside on a CU (512 blocks, 2/CU). With bx reversed for
// y<16 and forward for y>=16, every co-resident pair's step count sums to 34:
// (2*(15-x)+2) + (2*x+2) = 34 -> uniform CU load (was 4..64, heavy-with-heavy).
__global__ __launch_bounds__(512, 4) void attn_kernel(
    const __hip_bfloat16* __restrict__ q, const __hip_bfloat16* __restrict__ k,
    const __hip_bfloat16* __restrict__ vt, __hip_bfloat16* __restrict__ o) {
    __shared__ __hip_bfloat16 Ks[64][136];   // keys x d
    __shared__ __hip_bfloat16 Vs[128][72];   // d x keys
    __shared__ __hip_bfloat16 Ps[8][16][72]; // per-wave: qrow x key

    const int bh = blockIdx.y;
    const int bx = (bh < 16) ? (int)(gridDim.x - 1 - blockIdx.x) : (int)blockIdx.x;
    const int b = bh >> 4, h = bh & 15;
    const int kvh = h >> 2;
    const int t = threadIdx.x;
    const int w = t >> 6, lane = t & 63;
    const int lrow = lane & 15, quad = lane >> 4;
    const int q0 = bx * 128;
    const int qrow = q0 + w * 16 + lrow; // this lane's ONE q row (n-dim)
    const float scale = 0.08838834764831845f;

    // Q fragments, B-operand role: n=qrow (lrow), k=d (quad*8+j)
    const __hip_bfloat16* qp = q + ((size_t)((b * NH + h) * SEQ + qrow)) * HD;
    s16x8 qf[4];
    for (int ks = 0; ks < 4; ++ks) qf[ks] = *(const s16x8*)(qp + ks * 32 + quad * 8);

    float m_i = -1e30f, l_i = 0.f;
    f32x4 accO[8];
    f32x4 z4 = {0.f, 0.f, 0.f, 0.f};
    for (int d = 0; d < 8; ++d) accO[d] = z4;

    const __hip_bfloat16* kbase = k + ((size_t)(b * NKV + kvh) * SEQ) * HD;
    const __hip_bfloat16* vbase = vt + ((size_t)(b * NKV + kvh) * HD) * SEQ;

    s16x8 kr[2], vr[2];
    auto load_tile = [&](int kt) {
        for (int i = 0; i < 2; ++i) {
            int flat = (i * 512 + t) * 8;
            kr[i] = *(const s16x8*)(kbase + (size_t)(kt * 64 + (flat >> 7)) * HD + (flat & 127));
            vr[i] = *(const s16x8*)(vbase + (size_t)(flat >> 6) * SEQ + kt * 64 + (flat & 63));
        }
    };
    auto store_tile = [&]() {
        for (int i = 0; i < 2; ++i) {
            int flat = (i * 512 + t) * 8;
            *(s16x8*)&Ks[flat >> 7][flat & 127] = kr[i];
            *(s16x8*)&Vs[flat >> 6][flat & 63] = vr[i];
        }
    };

    const int nkt = 2 * bx + 2; // keys [0, q0+128)
    load_tile(0);
    store_tile();
    __syncthreads();

    for (int kt = 0; kt < nkt; ++kt) {
        bool more = (kt + 1) < nkt;
        if (more) load_tile(kt + 1);
        bool wave_active = (kt * 64 <= q0 + w * 16 + 15);
        bool mtile = (kt >= 2 * bx); // tile may touch the diagonal

        if (wave_active) {
            float sv[4][4];
            for (int nt = 0; nt < 4; ++nt) {
                f32x4 sacc = z4;
                for (int ks = 0; ks < 4; ++ks) {
                    s16x8 kf = *(const s16x8*)&Ks[nt * 16 + lrow][ks * 32 + quad * 8];
                    sacc = __builtin_amdgcn_mfma_f32_16x16x32_bf16(kf, qf[ks], sacc, 0, 0, 0);
                }
                for (int r = 0; r < 4; ++r) {
                    int key = kt * 64 + nt * 16 + quad * 4 + r;
                    sv[nt][r] = (mtile && key > qrow) ? -1e30f : sacc[r] * scale;
                }
            }
            float mt2 = -1e30f;
            for (int nt = 0; nt < 4; ++nt)
                for (int r = 0; r < 4; ++r) mt2 = fmaxf(mt2, sv[nt][r]);
            mt2 = fmaxf(mt2, __shfl_xor(mt2, 16, 64));
            mt2 = fmaxf(mt2, __shfl_xor(mt2, 32, 64));
            float mn = fmaxf(m_i, mt2);
            float alpha = __expf(m_i - mn);
            m_i = mn;
            float rs = 0.f;
            for (int nt = 0; nt < 4; ++nt) {
                short ph[4];
                for (int r = 0; r < 4; ++r) {
                    float p = __expf(sv[nt][r] - mn);
                    rs += p;
                    ph[r] = f2b_s(p);
                }
                *(s16x4*)&Ps[w][lrow][nt * 16 + quad * 4] = *(s16x4*)ph;
            }
            rs += __shfl_xor(rs, 16, 64);
            rs += __shfl_xor(rs, 32, 64);
            l_i = l_i * alpha + rs;
            for (int d = 0; d < 8; ++d)
                for (int r = 0; r < 4; ++r) accO[d][r] *= alpha;
            s16x8 pf0 = *(const s16x8*)&Ps[w][lrow][quad * 8];
            s16x8 pf1 = *(const s16x8*)&Ps[w][lrow][32 + quad * 8];
            for (int dt = 0; dt < 8; ++dt) {
                s16x8 vf0 = *(const s16x8*)&Vs[dt * 16 + lrow][quad * 8];
                s16x8 vf1 = *(const s16x8*)&Vs[dt * 16 + lrow][32 + quad * 8];
                accO[dt] = __builtin_amdgcn_mfma_f32_16x16x32_bf16(vf0, pf0, accO[dt], 0, 0, 0);
                accO[dt] = __builtin_amdgcn_mfma_f32_16x16x32_bf16(vf1, pf1, accO[dt], 0, 0, 0);
            }
        }

        __syncthreads();
        if (more) {
            store_tile();
            __syncthreads();
        }
    }
    float inv = 1.0f / l_i;
    __hip_bfloat16* op = o + (size_t)(b * SEQ + qrow) * DM + h * HD;
    for (int dt = 0; dt < 8; ++dt) {
        short ov[4];
        for (int r = 0; r < 4; ++r) ov[r] = f2b_s(accO[dt][r] * inv);
        *(s16x4*)(op + dt * 16 + quad * 4) = *(s16x4*)ov;
    }
}

extern "C" void kernel_launch(void* const* d_in, const int* in_sizes, int n_in,
                              void* d_out, int out_size, void* d_ws, size_t ws_size,
                              hipStream_t stream) {
    (void)in_sizes; (void)n_in; (void)out_size; (void)ws_size;
    const float* x  = (const float*)d_in[0];
    const float* fc = (const float*)d_in[1];
    const float* fs = (const float*)d_in[2];
    // d_in[3] = mask: exactly causal, applied analytically
    const float* wq = (const float*)d_in[4];
    const float* wk = (const float*)d_in[5];
    const float* wv = (const float*)d_in[6];
    const float* wo = (const float*)d_in[7];

    __hip_bfloat16* xb    = (__hip_bfloat16*)d_ws;            // [4096][2048]
    __hip_bfloat16* wqkvt = xb + (size_t)8388608;             // [3072][2048]
    __hip_bfloat16* wot   = wqkvt + (size_t)6291456;          // [2048][2048]
    __hip_bfloat16* qkv   = wot + (size_t)4194304;            // [4096][3072]
    __hip_bfloat16* qb    = xb;                               // aliases xb
    __hip_bfloat16* kb    = wqkvt;                            // aliases wqkvt
    __hip_bfloat16* vtb   = wqkvt + (size_t)2097152;
    __hip_bfloat16* attno = qkv;                              // aliases qkv

    cast_kernel<<<8192, 256, 0, stream>>>(x, xb, 8388608);
    transpose_cast<<<dim3(64, 64), dim3(32, 8), 0, stream>>>(wq, wqkvt, 2048, 2048);
    transpose_cast<<<dim3(16, 64), dim3(32, 8), 0, stream>>>(wk, wqkvt + (size_t)2048 * 2048, 2048, 512);
    transpose_cast<<<dim3(16, 64), dim3(32, 8), 0, stream>>>(wv, wqkvt + (size_t)2560 * 2048, 2048, 512);
    transpose_cast<<<dim3(64, 64), dim3(32, 8), 0, stream>>>(wo, wot, 2048, 2048);
    gemm_bt<0><<<dim3(24, 32), 256, 0, stream>>>(xb, wqkvt, qkv, 4096, 3072, 2048);
    rope_reshape<<<4096, 256, 0, stream>>>(qkv, fc, fs, qb, kb);
    vtrans<<<dim3(16, 8), 256, 0, stream>>>(qkv, vtb);
    attn_kernel<<<dim3(16, 32), 512, 0, stream>>>(qb, kb, vtb, attno);
    gemm_bt<1><<<dim3(16, 32), 256, 0, stream>>>(attno, wot, d_out, 4096, 2048, 2048);
}